// Round 3
// baseline (116697.412 us; speedup 1.0000x reference)
//
#include <hip/hip_runtime.h>
#include <math.h>

// ---------------------------------------------------------------------------
// Tacotron-style decoder scan on MI355X.
// Strategy: persistent 64-block kernel, hand-rolled grid barrier (3/step),
// phase-overlapped schedule, all step-invariant matmuls precomputed.
// ---------------------------------------------------------------------------

#define NBLK 64
#define NTHR 256

#define TENC 200
#define TDEC 200
#define G3   768   // 3*HID

// workspace float offsets
#define O_BAR   0
#define O_HA0   64
#define O_HA1   (O_HA0 + 8192)
#define O_ATTN  (O_HA1 + 8192)
#define O_H1    (O_ATTN + 8192)
#define O_H2    (O_H1 + 8192)
#define O_PROJ  (O_H2 + 8192)            // zero-init region ends here
#define O_R1    (O_PROJ + 8192)
#define O_RH1   (O_R1 + 8192)            // [32][768]
#define O_RH2   (O_RH1 + 24576)          // [32][768]
#define O_AX    (O_RH2 + 24576)          // [32][768] attn-GRU x-preact
#define O_Q2    (O_AX + 24576)           // [200][32][128]
#define O_WV    (O_Q2 + 200*32*128)      // [32][200][256]
#define O_R2    (O_WV + 32*200*256)      // [200][32][256]
#define ZERO_FLOATS O_PROJ

__device__ __forceinline__ float sigm(float x)  { return 1.0f / (1.0f + __expf(-x)); }
__device__ __forceinline__ float ftanh(float x) { return 1.0f - 2.0f / (1.0f + __expf(2.0f * x)); }

__device__ __forceinline__ void gridbar(unsigned* cnt, unsigned* gen) {
  __syncthreads();
  if (threadIdx.x == 0) {
    __threadfence();
    unsigned target = (*gen + 1u) * (unsigned)NBLK;
    atomicAdd(cnt, 1u);
    while (__hip_atomic_load(cnt, __ATOMIC_ACQUIRE, __HIP_MEMORY_SCOPE_AGENT) < target)
      __builtin_amdgcn_s_sleep(1);
    *gen = *gen + 1u;
  }
  __syncthreads();
}

// ---- phase: attn-GRU x-preactivation for step t:  ax = b_in + q@Ka1 + attn@Ka2
__device__ __forceinline__ void phase_ax(int t, int tid, int u0, int b0,
    const float* fAT, const float* fQ2, const float* aK, const float* aB,
    float* fAX, float* sh)
{
  float* sA = sh;            // [8][257]
  float* sQ = sh + 2056;     // [8][129]
  for (int i = tid; i < 2048; i += NTHR) {
    int bb = i >> 8, k = i & 255;
    sA[bb * 257 + k] = fAT[(b0 + bb) * 256 + k];
  }
  for (int i = tid; i < 1024; i += NTHR) {
    int bb = i >> 7, k = i & 127;
    sQ[bb * 129 + k] = fQ2[((t * 32) + b0 + bb) * 128 + k];
  }
  __syncthreads();
  int du = tid >> 3, lb = tid & 7;
  int u = u0 + du, b = b0 + lb;
  float xz = aB[u], xr = aB[256 + u], xh = aB[512 + u];
  #pragma unroll 4
  for (int k = 0; k < 128; ++k) {
    float q = sQ[lb * 129 + k];
    const float* row = aK + k * G3;
    xz += q * row[u]; xr += q * row[256 + u]; xh += q * row[512 + u];
  }
  #pragma unroll 4
  for (int k = 0; k < 256; ++k) {
    float a = sA[lb * 257 + k];
    const float* row = aK + (128 + k) * G3;
    xz += a * row[u]; xr += a * row[256 + u]; xh += a * row[512 + u];
  }
  fAX[b * G3 + u] = xz;
  fAX[b * G3 + 256 + u] = xr;
  fAX[b * G3 + 512 + u] = xh;
}

// ---- phase: attn-GRU recurrent part + combine -> h_a(t)
__device__ __forceinline__ void phase_a(int tid, int u0, int b0,
    const float* haPrev, float* haCur, const float* fAX,
    const float* aRK, const float* aB, float* sh)
{
  float* sH = sh;  // [8][257]
  for (int i = tid; i < 2048; i += NTHR) {
    int bb = i >> 8, k = i & 255;
    sH[bb * 257 + k] = haPrev[(b0 + bb) * 256 + k];
  }
  __syncthreads();
  int du = tid >> 3, lb = tid & 7;
  int u = u0 + du, b = b0 + lb;
  float rz = aB[768 + u], rr = aB[768 + 256 + u], rh = aB[768 + 512 + u];
  #pragma unroll 4
  for (int k = 0; k < 256; ++k) {
    float h = sH[lb * 257 + k];
    const float* row = aRK + k * G3;
    rz += h * row[u]; rr += h * row[256 + u]; rh += h * row[512 + u];
  }
  float xz = fAX[b * G3 + u], xr = fAX[b * G3 + 256 + u], xh = fAX[b * G3 + 512 + u];
  float z = sigm(xz + rz), r = sigm(xr + rr);
  float hh = ftanh(xh + r * rh);
  float hp = sH[lb * 257 + u];
  haCur[b * 256 + u] = z * hp + (1.0f - z) * hh;
}

// ---- phase: generic GRU (x-part from staged rows) + residual write
__device__ __forceinline__ void phase_rnn(int tid, int u0, int b0,
    const float* xrows, const float* frh, float* fh,
    const float* Kx, const float* Bx, float* resid_out, float* sh)
{
  float* sX = sh;  // [8][257]
  for (int i = tid; i < 2048; i += NTHR) {
    int bb = i >> 8, k = i & 255;
    sX[bb * 257 + k] = xrows[(b0 + bb) * 256 + k];
  }
  __syncthreads();
  int du = tid >> 3, lb = tid & 7;
  int u = u0 + du, b = b0 + lb;
  float xz = Bx[u], xr = Bx[256 + u], xh = Bx[512 + u];
  #pragma unroll 4
  for (int k = 0; k < 256; ++k) {
    float x = sX[lb * 257 + k];
    const float* row = Kx + k * G3;
    xz += x * row[u]; xr += x * row[256 + u]; xh += x * row[512 + u];
  }
  float rz = frh[b * G3 + u], rr = frh[b * G3 + 256 + u], rh = frh[b * G3 + 512 + u];
  float z = sigm(xz + rz), r = sigm(xr + rr);
  float hh = ftanh(xh + r * rh);
  float hp = fh[b * 256 + u];
  float hn = z * hp + (1.0f - z) * hh;
  fh[b * 256 + u] = hn;
  resid_out[b * 256 + u] = sX[lb * 257 + u] + hn;
}

// ---- phase: recurrent-gate GEMVs  rh1 = h1@RK1 + b1r, rh2 = h2@RK2 + b2r
__device__ __forceinline__ void phase_rh(int tid, int cg, int b0,
    const float* fH1, const float* fH2,
    const float* RK1, const float* B1v, const float* RK2, const float* B2v,
    float* fRH1, float* fRH2, float* sh)
{
  float* s1 = sh;            // [8][257]
  float* s2 = sh + 2056;     // [8][257]
  for (int i = tid; i < 2048; i += NTHR) {
    int bb = i >> 8, k = i & 255;
    s1[bb * 257 + k] = fH1[(b0 + bb) * 256 + k];
    s2[bb * 257 + k] = fH2[(b0 + bb) * 256 + k];
  }
  __syncthreads();
  int cc = tid >> 3, lb = tid & 7;
  int b = b0 + lb;
  #pragma unroll
  for (int j = 0; j < 3; ++j) {
    int col = cg * 96 + cc + j * 32;
    float a1 = B1v[768 + col], a2 = B2v[768 + col];
    #pragma unroll 4
    for (int k = 0; k < 256; ++k) {
      float h1v = s1[lb * 257 + k], h2v = s2[lb * 257 + k];
      a1 += h1v * RK1[k * G3 + col];
      a2 += h2v * RK2[k * G3 + col];
    }
    fRH1[b * G3 + col] = a1;
    fRH2[b * G3 + col] = a2;
  }
}

// ---- phase: Bahdanau attention + projection, one block per batch row
__device__ __forceinline__ void phase_b(int tid, int b,
    const float* haCur, const float* U, const float* V,
    const float* mem, const float* fWV,
    const float* Wp, const float* pb, float* fAT, float* fPJ, float* sh)
{
  float* sRow = sh;           // h_a row (256)
  float* sUv  = sh + 256;
  float* sSc  = sh + 512;
  float* sAl  = sh + 768;
  float* sAt  = sh + 1024;
  float* sRed = sh + 1280;    // 32
  sRow[tid] = haCur[b * 256 + tid];
  __syncthreads();
  {
    float acc = 0.f;
    #pragma unroll 4
    for (int k = 0; k < 256; ++k) acc += sRow[k] * U[k * 256 + tid];
    sUv[tid] = acc;
  }
  __syncthreads();
  {
    const int tq = tid >> 3, ds = tid & 7;
    float uvr[32], vvr[32];
    #pragma unroll
    for (int i = 0; i < 32; ++i) { uvr[i] = sUv[ds * 32 + i]; vvr[i] = V[ds * 32 + i]; }
    for (int p = 0; p < 7; ++p) {
      int tp = p * 32 + tq;
      float part = 0.f;
      if (tp < TENC) {
        const float* wvp = fWV + (b * TENC + tp) * 256 + ds * 32;
        #pragma unroll
        for (int i = 0; i < 32; ++i) part += ftanh(wvp[i] + uvr[i]) * vvr[i];
      }
      part += __shfl_down(part, 4, 8);
      part += __shfl_down(part, 2, 8);
      part += __shfl_down(part, 1, 8);
      if (ds == 0 && tp < TENC) sSc[tp] = part;
    }
  }
  __syncthreads();
  float s = (tid < TENC) ? sSc[tid] : -1e30f;
  float m = s;
  #pragma unroll
  for (int off = 32; off > 0; off >>= 1) m = fmaxf(m, __shfl_xor(m, off, 64));
  if ((tid & 63) == 0) sRed[tid >> 6] = m;
  __syncthreads();
  if (tid == 0) sRed[4] = fmaxf(fmaxf(sRed[0], sRed[1]), fmaxf(sRed[2], sRed[3]));
  __syncthreads();
  float M = sRed[4];
  float e = (tid < TENC) ? __expf(s - M) : 0.f;
  sAl[tid] = e;
  float zs = e;
  #pragma unroll
  for (int off = 32; off > 0; off >>= 1) zs += __shfl_xor(zs, off, 64);
  if ((tid & 63) == 0) sRed[8 + (tid >> 6)] = zs;
  __syncthreads();
  if (tid == 0) sRed[12] = sRed[8] + sRed[9] + sRed[10] + sRed[11];
  __syncthreads();
  float Zi = 1.0f / sRed[12];
  {
    float acc = 0.f;
    const float* mrow = mem + b * TENC * 256 + tid;
    #pragma unroll 4
    for (int t2 = 0; t2 < TENC; ++t2) acc += sAl[t2] * mrow[t2 * 256];
    float av = acc * Zi;
    sAt[tid] = av;
    fAT[b * 256 + tid] = av;
  }
  __syncthreads();
  {
    float acc = pb[tid];
    #pragma unroll 4
    for (int k = 0; k < 256; ++k) acc += sAt[k] * Wp[k * 256 + tid];
    #pragma unroll 4
    for (int k = 0; k < 256; ++k) acc += sRow[k] * Wp[(256 + k) * 256 + tid];
    fPJ[b * 256 + tid] = acc;
  }
}

// ---------------------------------------------------------------------------
__global__ __launch_bounds__(NTHR) void k_scan(
    const float* __restrict__ mem,
    const float* __restrict__ aK, const float* __restrict__ aRK, const float* __restrict__ aB,
    const float* __restrict__ U, const float* __restrict__ V,
    const float* __restrict__ Wp, const float* __restrict__ pb,
    const float* __restrict__ K1, const float* __restrict__ RK1, const float* __restrict__ B1v,
    const float* __restrict__ K2, const float* __restrict__ RK2, const float* __restrict__ B2v,
    float* __restrict__ ws)
{
  const int bid = blockIdx.x, tid = threadIdx.x;
  float* fHA0 = ws + O_HA0;
  float* fHA1 = ws + O_HA1;
  float* fAT  = ws + O_ATTN;
  float* fH1  = ws + O_H1;
  float* fH2  = ws + O_H2;
  float* fPJ  = ws + O_PROJ;
  float* fR1  = ws + O_R1;
  float* fRH1 = ws + O_RH1;
  float* fRH2 = ws + O_RH2;
  float* fAX  = ws + O_AX;
  float* fQ2  = ws + O_Q2;
  float* fWV  = ws + O_WV;
  float* fR2  = ws + O_R2;
  unsigned* cnt = (unsigned*)(ws + O_BAR);
  unsigned gen = 0;

  __shared__ float sh[4112];

  const int sb = bid & 31;
  const int ug = sb >> 2, bg = sb & 3;    // 8 unit-groups x 4 batch-groups
  const int u0 = ug * 32, b0 = bg * 8;

  // prologue: x-preactivation for step 0 (attn(-1)=0, zero-initialized)
  if (bid >= 32) phase_ax(0, tid, u0, b0, fAT, fQ2, aK, aB, fAX, sh);
  gridbar(cnt, &gen);

  for (int t = 0; t < TDEC; ++t) {
    float* haCur = (t & 1) ? fHA1 : fHA0;
    float* haPrv = (t & 1) ? fHA0 : fHA1;
    // slot1: attn-GRU combine  ||  RNN2 of step t-1
    if (bid < 32) phase_a(tid, u0, b0, haPrv, haCur, fAX, aRK, aB, sh);
    else if (t > 0) phase_rnn(tid, u0, b0, fR1, fRH2, fH2, K2, B2v,
                              fR2 + (size_t)(t - 1) * 8192, sh);
    gridbar(cnt, &gen);
    // slot2: attention + proj (block b)  ||  rh1/rh2 recurrent GEMVs
    if (bid < 32) phase_b(tid, bid, haCur, U, V, mem, fWV, Wp, pb, fAT, fPJ, sh);
    else phase_rh(tid, ug, b0, fH1, fH2, RK1, B1v, RK2, B2v, fRH1, fRH2, sh);
    gridbar(cnt, &gen);
    // slot3: RNN1  ||  x-preactivation for step t+1
    if (bid < 32) phase_rnn(tid, u0, b0, fPJ, fRH1, fH1, K1, B1v, fR1, sh);
    else if (t + 1 < TDEC) phase_ax(t + 1, tid, u0, b0, fAT, fQ2, aK, aB, fAX, sh);
    gridbar(cnt, &gen);
  }
  // epilogue: RNN2 of final step
  if (bid >= 32) phase_rnn(tid, u0, b0, fR1, fRH2, fH2, K2, B2v,
                           fR2 + (size_t)(TDEC - 1) * 8192, sh);
}

// ---------------------------------------------------------------------------
__global__ __launch_bounds__(256) void k_wv(
    const float* __restrict__ mem, const float* __restrict__ W, float* __restrict__ wv)
{
  const int tile = blockIdx.x, b = blockIdx.y;  // tile<25
  const int t0 = tile * 8, tid = threadIdx.x;
  __shared__ float rows[2048];
  for (int i = tid; i < 2048; i += 256) rows[i] = mem[(b * TENC + t0) * 256 + i];
  __syncthreads();
  float acc[8] = {0.f,0.f,0.f,0.f,0.f,0.f,0.f,0.f};
  for (int k = 0; k < 256; ++k) {
    float w = W[k * 256 + tid];
    #pragma unroll
    for (int tt = 0; tt < 8; ++tt) acc[tt] += rows[tt * 256 + k] * w;
  }
  #pragma unroll
  for (int tt = 0; tt < 8; ++tt) wv[(b * TENC + t0 + tt) * 256 + tid] = acc[tt];
}

__global__ __launch_bounds__(256) void k_prenet(
    const float* __restrict__ x, const float* __restrict__ w1, const float* __restrict__ b1,
    const float* __restrict__ w2, const float* __restrict__ b2, float* __restrict__ q2)
{
  const int tile = blockIdx.x, b = blockIdx.y;  // tile<50
  const int t0 = tile * 4, tid = threadIdx.x;
  __shared__ float xr[320];
  __shared__ float q1[1024];
  for (int i = tid; i < 320; i += 256) {
    int tt = i / 80, k = i - tt * 80;
    xr[i] = x[(b * TDEC + t0 + tt) * 80 + k];
  }
  __syncthreads();
  {
    float a0 = 0.f, a1 = 0.f, a2 = 0.f, a3 = 0.f;
    for (int k = 0; k < 80; ++k) {
      float w = w1[k * 256 + tid];
      a0 += xr[k] * w; a1 += xr[80 + k] * w; a2 += xr[160 + k] * w; a3 += xr[240 + k] * w;
    }
    float bb = b1[tid];
    q1[tid]       = fmaxf(a0 + bb, 0.f);
    q1[256 + tid] = fmaxf(a1 + bb, 0.f);
    q1[512 + tid] = fmaxf(a2 + bb, 0.f);
    q1[768 + tid] = fmaxf(a3 + bb, 0.f);
  }
  __syncthreads();
  {
    const int j = tid & 127, tp = tid >> 7;  // two timesteps per half-block
    float c0 = 0.f, c1 = 0.f;
    for (int k = 0; k < 256; ++k) {
      float w = w2[k * 128 + j];
      c0 += q1[(2 * tp) * 256 + k] * w;
      c1 += q1[(2 * tp + 1) * 256 + k] * w;
    }
    float bb = b2[j];
    q2[((t0 + 2 * tp) * 32 + b) * 128 + j]     = fmaxf(c0 + bb, 0.f);
    q2[((t0 + 2 * tp + 1) * 32 + b) * 128 + j] = fmaxf(c1 + bb, 0.f);
  }
}

__global__ __launch_bounds__(128) void k_out(
    const float* __restrict__ r2, const float* __restrict__ wo,
    const float* __restrict__ bo, float* __restrict__ out)
{
  const int tb = blockIdx.x;  // t*32 + b
  const int t = tb >> 5, b = tb & 31, tid = threadIdx.x;
  __shared__ float row[256];
  for (int i = tid; i < 256; i += 128) row[i] = r2[(size_t)tb * 256 + i];
  __syncthreads();
  if (tid < 80) {
    float acc = bo[tid];
    #pragma unroll 4
    for (int k = 0; k < 256; ++k) acc += row[k] * wo[k * 80 + tid];
    out[(b * TDEC + t) * 80 + tid] = acc;
  }
}

// ---------------------------------------------------------------------------
extern "C" void kernel_launch(void* const* d_in, const int* in_sizes, int n_in,
                              void* d_out, int out_size, void* d_ws, size_t ws_size,
                              hipStream_t stream)
{
  const float* mem = (const float*)d_in[0];
  const float* dec = (const float*)d_in[1];
  const float* w1  = (const float*)d_in[2];
  const float* b1  = (const float*)d_in[3];
  const float* w2  = (const float*)d_in[4];
  const float* b2  = (const float*)d_in[5];
  const float* aK  = (const float*)d_in[6];
  const float* aRK = (const float*)d_in[7];
  const float* aB  = (const float*)d_in[8];
  const float* W   = (const float*)d_in[9];
  const float* U   = (const float*)d_in[10];
  const float* V   = (const float*)d_in[11];
  const float* Wp  = (const float*)d_in[12];
  const float* pb  = (const float*)d_in[13];
  const float* K1  = (const float*)d_in[14];
  const float* RK1 = (const float*)d_in[15];
  const float* B1v = (const float*)d_in[16];
  const float* K2  = (const float*)d_in[17];
  const float* RK2 = (const float*)d_in[18];
  const float* B2v = (const float*)d_in[19];
  const float* Wo  = (const float*)d_in[20];
  const float* bo  = (const float*)d_in[21];
  float* ws  = (float*)d_ws;
  float* out = (float*)d_out;

  hipMemsetAsync(ws, 0, (size_t)ZERO_FLOATS * sizeof(float), stream);
  k_wv<<<dim3(25, 32), 256, 0, stream>>>(mem, W, ws + O_WV);
  k_prenet<<<dim3(50, 32), 256, 0, stream>>>(dec, w1, b1, w2, b2, ws + O_Q2);
  k_scan<<<NBLK, NTHR, 0, stream>>>(mem, aK, aRK, aB, U, V, Wp, pb,
                                    K1, RK1, B1v, K2, RK2, B2v, ws);
  k_out<<<6400, 128, 0, stream>>>(ws + O_R2, Wo, bo, out);
}

// Round 4
// 9984.665 us; speedup vs baseline: 11.6877x; 11.6877x over previous
//
#include <hip/hip_runtime.h>
#include <math.h>

// ---------------------------------------------------------------------------
// Tacotron-style decoder scan on MI355X — zero-grid-barrier pipeline.
// 128 blocks = 4 stages x 32 batch rows. Per-batch stage pipeline with
// single-writer/single-reader step flags (relaxed spin + fence). All
// recurrent state lives in LDS; weights stream from L2.
// ---------------------------------------------------------------------------

#define TENC 200
#define TDEC 200
#define HID  256
#define G3   768
#define NT   1024

// workspace float offsets
#define O_FLAG 0                         // 4096 floats zeroed (3 flag arrays)
#define O_HAS  4096                      // h_a stream   [200][32][256]
#define O_ATS  (O_HAS + TDEC*32*256)     // attn stream  [200][32][256]
#define O_R1S  (O_ATS + TDEC*32*256)     // r1 stream    [200][32][256]
#define O_R2S  (O_R1S + TDEC*32*256)     // r2 stream    [200][32][256]
#define O_Q2   (O_R2S + TDEC*32*256)     // prenet out   [200][32][128]
#define O_WV   (O_Q2  + TDEC*32*128)     // memory@W     [32][200][256]
#define ZERO_FLOATS 4096

__device__ __forceinline__ float sigm(float x)  { return 1.0f / (1.0f + __expf(-x)); }
__device__ __forceinline__ float ftanh(float x) { return 1.0f - 2.0f / (1.0f + __expf(2.0f * x)); }

// single-reader spin: RELAXED polls (no per-poll cache invalidate), one fence after.
__device__ __forceinline__ void flag_wait(const unsigned* f, unsigned target) {
  if (threadIdx.x == 0) {
    while (__hip_atomic_load(f, __ATOMIC_RELAXED, __HIP_MEMORY_SCOPE_AGENT) < target)
      __builtin_amdgcn_s_sleep(8);
    __threadfence();
  }
  __syncthreads();
}
// single-writer publish: fence (write back data), then relaxed store.
__device__ __forceinline__ void flag_set(unsigned* f, unsigned v) {
  __syncthreads();
  if (threadIdx.x == 0) {
    __threadfence();
    __hip_atomic_store(f, v, __ATOMIC_RELAXED, __HIP_MEMORY_SCOPE_AGENT);
  }
}

// 3-gate GEMV partial: out[g*256+u] = sum_k x[k]*W[k][g*256+u], K split in 4 over kq.
__device__ __forceinline__ void gemv3_partial(int tid, int K, const float* __restrict__ W,
                                              const float* xbuf, float* sPart) {
  const int u = tid & 255, kq = tid >> 8;
  const int kc = K >> 2;
  const int k0 = kq * kc, k1 = k0 + kc;
  float a0 = 0.f, a1 = 0.f, a2 = 0.f;
  #pragma unroll 4
  for (int k = k0; k < k1; ++k) {
    float x = xbuf[k];
    const float* row = W + (size_t)k * G3;
    a0 += x * row[u]; a1 += x * row[256 + u]; a2 += x * row[512 + u];
  }
  sPart[(kq * 3 + 0) * 256 + u] = a0;
  sPart[(kq * 3 + 1) * 256 + u] = a1;
  sPart[(kq * 3 + 2) * 256 + u] = a2;
}
__device__ __forceinline__ float gsum4(const float* sPart, int g, int u) {
  return sPart[(0*3+g)*256+u] + sPart[(1*3+g)*256+u] + sPart[(2*3+g)*256+u] + sPart[(3*3+g)*256+u];
}
// 1-gate GEMV partial, O=256, row stride 256
__device__ __forceinline__ void gemv1_partial(int tid, int K, const float* __restrict__ W,
                                              const float* xbuf, float* sP) {
  const int u = tid & 255, kq = tid >> 8;
  const int kc = K >> 2;
  float a = 0.f;
  #pragma unroll 4
  for (int k = kq * kc; k < kq * kc + kc; ++k) a += xbuf[k] * W[(size_t)k * 256 + u];
  sP[kq * 256 + u] = a;
}

// ---------------------------------------------------------------------------
__global__ __launch_bounds__(NT) void k_scan4(
    const float* __restrict__ mem,
    const float* __restrict__ aK, const float* __restrict__ aRK, const float* __restrict__ aB,
    const float* __restrict__ U, const float* __restrict__ V,
    const float* __restrict__ Wp, const float* __restrict__ pb,
    const float* __restrict__ K1, const float* __restrict__ RK1, const float* __restrict__ B1v,
    const float* __restrict__ K2, const float* __restrict__ RK2, const float* __restrict__ B2v,
    float* __restrict__ ws)
{
  const int bid = blockIdx.x, tid = threadIdx.x;
  const int stage = bid >> 5, b = bid & 31;

  float* fHAS = ws + O_HAS;
  float* fATS = ws + O_ATS;
  float* fR1S = ws + O_R1S;
  float* fR2S = ws + O_R2S;
  float* fQ2  = ws + O_Q2;
  float* fWV  = ws + O_WV;
  unsigned* fl = (unsigned*)(ws + O_FLAG);
  unsigned* flagHA = fl + b * 32;            // A -> B
  unsigned* flagAT = fl + 1024 + b * 32;     // B -> A (next step), B -> C
  unsigned* flagR1 = fl + 2048 + b * 32;     // C -> D

  __shared__ float sh[4864];

  if (stage == 0) {
    // ---- stage A: attn-GRU.  x = [q(128) | attn(256)] @ aK ; rec = h_a @ aRK
    float* sX    = sh;            // 384
    float* sHA   = sh + 384;      // 256
    float* sAX   = sh + 640;      // 768
    float* sPart = sh + 1408;     // 3072
    if (tid < 256) sHA[tid] = 0.f;
    __syncthreads();
    for (int t = 0; t < TDEC; ++t) {
      if (t > 0) flag_wait(flagAT, (unsigned)t);     // attn(t-1) ready
      if (tid < 128) sX[tid] = fQ2[((size_t)t * 32 + b) * 128 + tid];
      else if (tid < 384) sX[tid] = (t > 0) ? fATS[(((size_t)t - 1) * 32 + b) * 256 + (tid - 128)] : 0.f;
      __syncthreads();
      gemv3_partial(tid, 384, aK, sX, sPart);
      __syncthreads();
      if (tid < 768) {
        int g = tid >> 8, u = tid & 255;
        sAX[tid] = gsum4(sPart, g, u) + aB[tid];     // + input bias
      }
      __syncthreads();
      gemv3_partial(tid, 256, aRK, sHA, sPart);
      __syncthreads();
      if (tid < 256) {
        int u = tid;
        float rz = gsum4(sPart, 0, u) + aB[768 + u];
        float rr = gsum4(sPart, 1, u) + aB[1024 + u];
        float rh = gsum4(sPart, 2, u) + aB[1280 + u];
        float z  = sigm(sAX[u] + rz);
        float r  = sigm(sAX[256 + u] + rr);
        float hh = ftanh(sAX[512 + u] + r * rh);
        float hn = z * sHA[u] + (1.0f - z) * hh;
        sHA[u] = hn;
        fHAS[((size_t)t * 32 + b) * 256 + u] = hn;
      }
      flag_set(flagHA, (unsigned)(t + 1));
    }
  } else if (stage == 1) {
    // ---- stage B: Bahdanau attention -> attn(t)
    float* sHAr = sh;           // 256
    float* sUh  = sh + 256;     // 256
    float* sSc  = sh + 512;     // 256
    float* sAl  = sh + 768;     // 256
    float* sPU  = sh + 1024;    // 1024
    float* sRed = sh + 2048;    // 16
    for (int t = 0; t < TDEC; ++t) {
      flag_wait(flagHA, (unsigned)(t + 1));
      if (tid < 256) sHAr[tid] = fHAS[((size_t)t * 32 + b) * 256 + tid];
      __syncthreads();
      gemv1_partial(tid, 256, U, sHAr, sPU);          // Uh = h_a @ U
      __syncthreads();
      if (tid < 256) sUh[tid] = sPU[tid] + sPU[256 + tid] + sPU[512 + tid] + sPU[768 + tid];
      __syncthreads();
      {   // scores: row r, quarter q of d-dim
        int r = tid >> 2, q = tid & 3;
        float part = 0.f;
        if (r < TENC) {
          const float* wv = fWV + ((size_t)b * TENC + r) * 256 + q * 64;
          const float* uh = sUh + q * 64;
          const float* vv = V + q * 64;
          #pragma unroll 8
          for (int i = 0; i < 64; ++i) part += ftanh(wv[i] + uh[i]) * vv[i];
        }
        part += __shfl_down(part, 2, 4);
        part += __shfl_down(part, 1, 4);
        if (r < TENC && q == 0) sSc[r] = part;
      }
      __syncthreads();
      if (tid < 256) {
        float s = (tid < TENC) ? sSc[tid] : -3.0e38f;
        float m = s;
        #pragma unroll
        for (int off = 32; off > 0; off >>= 1) m = fmaxf(m, __shfl_xor(m, off, 64));
        if ((tid & 63) == 0) sRed[tid >> 6] = m;
      }
      __syncthreads();
      if (tid < 256) {
        float M = fmaxf(fmaxf(sRed[0], sRed[1]), fmaxf(sRed[2], sRed[3]));
        float s = (tid < TENC) ? sSc[tid] : -3.0e38f;
        float e = (tid < TENC) ? __expf(s - M) : 0.f;
        sAl[tid] = e;
        float zz = e;
        #pragma unroll
        for (int off = 32; off > 0; off >>= 1) zz += __shfl_xor(zz, off, 64);
        if ((tid & 63) == 0) sRed[8 + (tid >> 6)] = zz;
      }
      __syncthreads();
      {   // context: attn[d] = sum_t al[t]*mem[b][t][d]
        int d = tid & 255, kq = tid >> 8;
        const float* mb = mem + (size_t)b * TENC * 256;
        float acc = 0.f;
        #pragma unroll 2
        for (int t2 = kq * 50; t2 < kq * 50 + 50; ++t2) acc += sAl[t2] * mb[(size_t)t2 * 256 + d];
        sPU[kq * 256 + d] = acc;
      }
      __syncthreads();
      if (tid < 256) {
        float Z  = sRed[8] + sRed[9] + sRed[10] + sRed[11];
        float av = (sPU[tid] + sPU[256 + tid] + sPU[512 + tid] + sPU[768 + tid]) / Z;
        fATS[((size_t)t * 32 + b) * 256 + tid] = av;
      }
      flag_set(flagAT, (unsigned)(t + 1));
    }
  } else if (stage == 2) {
    // ---- stage C: proj + RNN1 -> r1(t)
    float* sXC   = sh;            // 512 = [attn | h_a]
    float* sPJ   = sh + 512;      // 256
    float* sH1   = sh + 768;      // 256
    float* sXP   = sh + 1024;     // 768
    float* sPart = sh + 1792;     // 3072
    if (tid < 256) sH1[tid] = 0.f;
    __syncthreads();
    for (int t = 0; t < TDEC; ++t) {
      flag_wait(flagAT, (unsigned)(t + 1));   // attn(t) ready => h_a(t) ready (transitive)
      if (tid < 256) sXC[tid] = fATS[((size_t)t * 32 + b) * 256 + tid];
      else if (tid < 512) sXC[tid] = fHAS[((size_t)t * 32 + b) * 256 + (tid - 256)];
      __syncthreads();
      gemv1_partial(tid, 512, Wp, sXC, sPart);
      __syncthreads();
      if (tid < 256) sPJ[tid] = sPart[tid] + sPart[256 + tid] + sPart[512 + tid] + sPart[768 + tid] + pb[tid];
      __syncthreads();
      gemv3_partial(tid, 256, K1, sPJ, sPart);
      __syncthreads();
      if (tid < 768) {
        int g = tid >> 8, u = tid & 255;
        sXP[tid] = gsum4(sPart, g, u) + B1v[tid];
      }
      __syncthreads();
      gemv3_partial(tid, 256, RK1, sH1, sPart);
      __syncthreads();
      if (tid < 256) {
        int u = tid;
        float rz = gsum4(sPart, 0, u) + B1v[768 + u];
        float rr = gsum4(sPart, 1, u) + B1v[1024 + u];
        float rh = gsum4(sPart, 2, u) + B1v[1280 + u];
        float z  = sigm(sXP[u] + rz);
        float r  = sigm(sXP[256 + u] + rr);
        float hh = ftanh(sXP[512 + u] + r * rh);
        float hn = z * sH1[u] + (1.0f - z) * hh;
        sH1[u] = hn;
        fR1S[((size_t)t * 32 + b) * 256 + u] = sPJ[u] + hn;
      }
      flag_set(flagR1, (unsigned)(t + 1));
    }
  } else {
    // ---- stage D: RNN2 -> r2(t)
    float* sR1   = sh;            // 256
    float* sH2   = sh + 256;      // 256
    float* sXP   = sh + 512;      // 768
    float* sPart = sh + 1280;     // 3072
    if (tid < 256) sH2[tid] = 0.f;
    __syncthreads();
    for (int t = 0; t < TDEC; ++t) {
      flag_wait(flagR1, (unsigned)(t + 1));
      if (tid < 256) sR1[tid] = fR1S[((size_t)t * 32 + b) * 256 + tid];
      __syncthreads();
      gemv3_partial(tid, 256, K2, sR1, sPart);
      __syncthreads();
      if (tid < 768) {
        int g = tid >> 8, u = tid & 255;
        sXP[tid] = gsum4(sPart, g, u) + B2v[tid];
      }
      __syncthreads();
      gemv3_partial(tid, 256, RK2, sH2, sPart);
      __syncthreads();
      if (tid < 256) {
        int u = tid;
        float rz = gsum4(sPart, 0, u) + B2v[768 + u];
        float rr = gsum4(sPart, 1, u) + B2v[1024 + u];
        float rh = gsum4(sPart, 2, u) + B2v[1280 + u];
        float z  = sigm(sXP[u] + rz);
        float r  = sigm(sXP[256 + u] + rr);
        float hh = ftanh(sXP[512 + u] + r * rh);
        float hn = z * sH2[u] + (1.0f - z) * hh;
        sH2[u] = hn;
        fR2S[((size_t)t * 32 + b) * 256 + u] = sR1[u] + hn;
      }
      __syncthreads();   // keep sR1/sH2 stable until writes done
    }
  }
}

// ---------------------------------------------------------------------------
__global__ __launch_bounds__(256) void k_wv(
    const float* __restrict__ mem, const float* __restrict__ W, float* __restrict__ wv)
{
  const int tile = blockIdx.x, b = blockIdx.y;  // tile<25
  const int t0 = tile * 8, tid = threadIdx.x;
  __shared__ float rows[2048];
  for (int i = tid; i < 2048; i += 256) rows[i] = mem[((size_t)b * TENC + t0) * 256 + i];
  __syncthreads();
  float acc[8] = {0.f,0.f,0.f,0.f,0.f,0.f,0.f,0.f};
  for (int k = 0; k < 256; ++k) {
    float w = W[(size_t)k * 256 + tid];
    #pragma unroll
    for (int tt = 0; tt < 8; ++tt) acc[tt] += rows[tt * 256 + k] * w;
  }
  #pragma unroll
  for (int tt = 0; tt < 8; ++tt) wv[((size_t)b * TENC + t0 + tt) * 256 + tid] = acc[tt];
}

__global__ __launch_bounds__(256) void k_prenet(
    const float* __restrict__ x, const float* __restrict__ w1, const float* __restrict__ b1,
    const float* __restrict__ w2, const float* __restrict__ b2, float* __restrict__ q2)
{
  const int tile = blockIdx.x, b = blockIdx.y;  // tile<50
  const int t0 = tile * 4, tid = threadIdx.x;
  __shared__ float xr[320];
  __shared__ float q1[1024];
  for (int i = tid; i < 320; i += 256) {
    int tt = i / 80, k = i - tt * 80;
    xr[i] = x[((size_t)b * TDEC + t0 + tt) * 80 + k];
  }
  __syncthreads();
  {
    float a0 = 0.f, a1 = 0.f, a2 = 0.f, a3 = 0.f;
    for (int k = 0; k < 80; ++k) {
      float w = w1[(size_t)k * 256 + tid];
      a0 += xr[k] * w; a1 += xr[80 + k] * w; a2 += xr[160 + k] * w; a3 += xr[240 + k] * w;
    }
    float bb = b1[tid];
    q1[tid]       = fmaxf(a0 + bb, 0.f);
    q1[256 + tid] = fmaxf(a1 + bb, 0.f);
    q1[512 + tid] = fmaxf(a2 + bb, 0.f);
    q1[768 + tid] = fmaxf(a3 + bb, 0.f);
  }
  __syncthreads();
  {
    const int j = tid & 127, tp = tid >> 7;
    float c0 = 0.f, c1 = 0.f;
    for (int k = 0; k < 256; ++k) {
      float w = w2[(size_t)k * 128 + j];
      c0 += q1[(2 * tp) * 256 + k] * w;
      c1 += q1[(2 * tp + 1) * 256 + k] * w;
    }
    float bb = b2[j];
    q2[(((size_t)t0 + 2 * tp) * 32 + b) * 128 + j]     = fmaxf(c0 + bb, 0.f);
    q2[(((size_t)t0 + 2 * tp + 1) * 32 + b) * 128 + j] = fmaxf(c1 + bb, 0.f);
  }
}

__global__ __launch_bounds__(128) void k_out(
    const float* __restrict__ r2, const float* __restrict__ wo,
    const float* __restrict__ bo, float* __restrict__ out)
{
  const int tb = blockIdx.x;  // t*32 + b
  const int t = tb >> 5, b = tb & 31, tid = threadIdx.x;
  __shared__ float row[256];
  for (int i = tid; i < 256; i += 128) row[i] = r2[(size_t)tb * 256 + i];
  __syncthreads();
  if (tid < 80) {
    float acc = bo[tid];
    #pragma unroll 4
    for (int k = 0; k < 256; ++k) acc += row[k] * wo[(size_t)k * 80 + tid];
    out[((size_t)b * TDEC + t) * 80 + tid] = acc;
  }
}

// ---------------------------------------------------------------------------
extern "C" void kernel_launch(void* const* d_in, const int* in_sizes, int n_in,
                              void* d_out, int out_size, void* d_ws, size_t ws_size,
                              hipStream_t stream)
{
  const float* mem = (const float*)d_in[0];
  const float* dec = (const float*)d_in[1];
  const float* w1  = (const float*)d_in[2];
  const float* b1  = (const float*)d_in[3];
  const float* w2  = (const float*)d_in[4];
  const float* b2  = (const float*)d_in[5];
  const float* aK  = (const float*)d_in[6];
  const float* aRK = (const float*)d_in[7];
  const float* aB  = (const float*)d_in[8];
  const float* W   = (const float*)d_in[9];
  const float* U   = (const float*)d_in[10];
  const float* V   = (const float*)d_in[11];
  const float* Wp  = (const float*)d_in[12];
  const float* pb  = (const float*)d_in[13];
  const float* K1  = (const float*)d_in[14];
  const float* RK1 = (const float*)d_in[15];
  const float* B1v = (const float*)d_in[16];
  const float* K2  = (const float*)d_in[17];
  const float* RK2 = (const float*)d_in[18];
  const float* B2v = (const float*)d_in[19];
  const float* Wo  = (const float*)d_in[20];
  const float* bo  = (const float*)d_in[21];
  float* ws  = (float*)d_ws;
  float* out = (float*)d_out;

  hipMemsetAsync(ws, 0, (size_t)ZERO_FLOATS * sizeof(float), stream);
  k_wv<<<dim3(25, 32), 256, 0, stream>>>(mem, W, ws + O_WV);
  k_prenet<<<dim3(50, 32), 256, 0, stream>>>(dec, w1, b1, w2, b2, ws + O_Q2);
  k_scan4<<<128, NT, 0, stream>>>(mem, aK, aRK, aB, U, V, Wp, pb,
                                  K1, RK1, B1v, K2, RK2, B2v, ws);
  k_out<<<6400, 128, 0, stream>>>(ws + O_R2S, Wo, bo, out);
}

// Round 5
// 8826.011 us; speedup vs baseline: 13.2220x; 1.1313x over previous
//
#include <hip/hip_runtime.h>
#include <math.h>

// ---------------------------------------------------------------------------
// Tacotron decoder scan, MI355X. Unit-split MFMA pipeline, zero grid barriers.
// 224 blocks: A(32)=attn-GRU, Bp(128)=Bahdanau partials, C(32)=proj+GRU1,
// D(32)=GRU2. Weights as split-bf16 images, LDS-persistent per block.
// ---------------------------------------------------------------------------

#define TENC 200
#define TDEC 200

typedef short bf16x8 __attribute__((ext_vector_type(8)));
typedef float f32x4  __attribute__((ext_vector_type(4)));

// ---- ws float offsets -----------------------------------------------------
#define O_H1B   1024                    // [2][32][256] h1 parity
#define O_H2B   17408                   // [2][32][256] h2 parity
#define O_R1B   33792                   // [2][32][256] r1 parity
#define ZERO_FLOATS 50176               // counters + parity zeroed
#define O_HAS   50176                   // [200][32][256] h_a stream
#define O_UHP   1688576                 // [32][32][256] Uh partials
#define O_NP    1950720                 // [2][128][256] context partials
#define O_ZP    2016256                 // [2][128]
#define O_PJ    2016512                 // [32][256] proj
#define O_Q2    2024704                 // [200][32][128] prenet out
#define O_WV    2843904                 // [32][200][256] memory@W
#define O_R2S   4482304                 // [200][32][256] r2 stream
#define O_IMG   6120704                 // bf16 weight images start (ushort*)

// image offsets in ushorts
#define IMGA_OFF  0u                    // [32][2][32][648]
#define IMGC1_OFF 1327104u              // [32][2][16][520]
#define IMGC2_OFF 1859584u              // [32][2][32][520]
#define IMGD_OFF  2924544u              // [32][2][32][520]

__device__ __forceinline__ float sigm(float x)  { return 1.0f / (1.0f + __expf(-x)); }
__device__ __forceinline__ float ftanh(float x) { return 1.0f - 2.0f / (1.0f + __expf(2.0f * x)); }

__device__ __forceinline__ unsigned short f2bf(float f) {
  union { float f; unsigned u; } v; v.f = f;
  return (unsigned short)((v.u + 0x7FFFu + ((v.u >> 16) & 1u)) >> 16);
}
__device__ __forceinline__ float bf2f(unsigned short h) {
  union { unsigned u; float f; } v; v.u = ((unsigned)h) << 16; return v.f;
}

__device__ __forceinline__ void waitc(unsigned* c, unsigned target) {
  if (threadIdx.x == 0) {
    while (__hip_atomic_load(c, __ATOMIC_RELAXED, __HIP_MEMORY_SCOPE_AGENT) < target)
      __builtin_amdgcn_s_sleep(4);
    __threadfence();
  }
  __syncthreads();
}
__device__ __forceinline__ void bump(unsigned* c) {
  __syncthreads();
  if (threadIdx.x == 0) { __threadfence(); atomicAdd(c, 1u); }
}

// ---------------------------------------------------------------------------
// k_prep: build split-bf16 weight images. y: 0=A,1=C1,2=C2,3=D
__global__ __launch_bounds__(256) void k_prep(
    const float* __restrict__ aK, const float* __restrict__ aRK,
    const float* __restrict__ Wp,
    const float* __restrict__ K1, const float* __restrict__ RK1,
    const float* __restrict__ K2, const float* __restrict__ RK2,
    unsigned short* __restrict__ img)
{
  int e = blockIdx.x * 256 + threadIdx.x;
  int id = blockIdx.y;
  float w = 0.f; size_t oh = 0, ol = 0;
  if (id == 0) {
    if (e >= 32*32*648) return;
    int k = e % 648, n = (e / 648) & 31, blk = e / (648*32);
    int u = blk*8 + (n & 7), g = n >> 3;
    if (k < 384) {
      w = (g==0) ? aK[(size_t)k*768+u] : (g==1) ? aK[(size_t)k*768+256+u]
        : (g==2) ? aK[(size_t)k*768+512+u] : 0.f;
    } else if (k < 640) {
      int kk = k - 384;
      w = (g==0) ? aRK[(size_t)kk*768+u] : (g==1) ? aRK[(size_t)kk*768+256+u]
        : (g==3) ? aRK[(size_t)kk*768+512+u] : 0.f;
    }
    size_t base = IMGA_OFF + (size_t)blk*2*32*648;
    oh = base + (size_t)n*648 + k; ol = oh + 32*648;
  } else if (id == 1) {
    if (e >= 32*16*520) return;
    int k = e % 520, n = (e / 520) & 15, blk = e / (520*16);
    if (n < 8 && k < 512) w = Wp[(size_t)k*256 + blk*8 + n];
    size_t base = IMGC1_OFF + (size_t)blk*2*16*520;
    oh = base + (size_t)n*520 + k; ol = oh + 16*520;
  } else {
    if (e >= 32*32*520) return;
    int k = e % 520, n = (e / 520) & 31, blk = e / (520*32);
    int u = blk*8 + (n & 7), g = n >> 3;
    const float* Kx = (id == 2) ? K1 : K2;
    const float* Rx = (id == 2) ? RK1 : RK2;
    if (k < 256) {
      w = (g==0) ? Kx[(size_t)k*768+u] : (g==1) ? Kx[(size_t)k*768+256+u]
        : (g==2) ? Kx[(size_t)k*768+512+u] : 0.f;
    } else if (k < 512) {
      int kk = k - 256;
      w = (g==0) ? Rx[(size_t)kk*768+u] : (g==1) ? Rx[(size_t)kk*768+256+u]
        : (g==3) ? Rx[(size_t)kk*768+512+u] : 0.f;
    }
    size_t base = ((id == 2) ? IMGC2_OFF : IMGD_OFF) + (size_t)blk*2*32*520;
    oh = base + (size_t)n*520 + k; ol = oh + 32*520;
  }
  unsigned short hi = f2bf(w);
  unsigned short lo = f2bf(w - bf2f(hi));
  img[oh] = hi; img[ol] = lo;
}

// ---------------------------------------------------------------------------
__global__ __launch_bounds__(256, 1) void k_scan5(
    const float* __restrict__ memg,
    const float* __restrict__ aB, const float* __restrict__ Uw,
    const float* __restrict__ Vw, const float* __restrict__ pb,
    const float* __restrict__ B1v, const float* __restrict__ B2v,
    float* __restrict__ ws)
{
  const int tid = threadIdx.x, bid = blockIdx.x;
  const int lane = tid & 63, wv = tid >> 6;
  unsigned* wsu = (unsigned*)ws;
  unsigned* cA  = wsu;       unsigned* cB  = wsu + 32;
  unsigned* cC1 = wsu + 64;  unsigned* cC2 = wsu + 96;
  unsigned* cD  = wsu + 128;
  float* fH1B = ws + O_H1B;  float* fH2B = ws + O_H2B;  float* fR1B = ws + O_R1B;
  float* fHAS = ws + O_HAS;  float* fUHP = ws + O_UHP;
  float* fNP  = ws + O_NP;   float* fZP  = ws + O_ZP;   float* fPJ = ws + O_PJ;
  float* fQ2  = ws + O_Q2;   float* fWV  = ws + O_WV;   float* fR2S = ws + O_R2S;
  const unsigned short* img = (const unsigned short*)(ws + O_IMG);

  __shared__ __align__(16) char smem[140544];

  if (bid < 32) {
    // ================= stage A: attn-GRU (8 units) + Uh partials ===========
    const int j = bid;
    unsigned short* sW = (unsigned short*)smem;            // [2][32][648]
    unsigned short* sX = (unsigned short*)(smem + 82944);  // [32][648]
    float* sU  = (float*)(smem + 124416);                  // [8][256]
    float* sOut= (float*)(smem + 132608);                  // [32][36]
    float* sHN = (float*)(smem + 137216);                  // [32][8]
    float* sHP = (float*)(smem + 138240);                  // [32][8]
    float* sB  = (float*)(smem + 139264);                  // [4][8]
    float* sZi = (float*)(smem + 139392);                  // [32]
    {
      const uint4* src = (const uint4*)(img + IMGA_OFF + (size_t)j*2*32*648);
      uint4* dst = (uint4*)sW;
      for (int i = tid; i < 82944/16; i += 256) dst[i] = src[i];
      for (int i = tid; i < 2048; i += 256)
        sU[i] = Uw[(size_t)(j*8 + (i >> 8))*256 + (i & 255)];
      if (tid < 8) {
        int u = j*8 + tid;
        sB[tid]      = aB[u]       + aB[768 + u];
        sB[8 + tid]  = aB[256 + u] + aB[1024 + u];
        sB[16 + tid] = aB[512 + u];
        sB[24 + tid] = aB[1280 + u];
      }
    }
    __syncthreads();
    for (int t = 0; t < TDEC; ++t) {
      if (t > 0) waitc(cB, 128u * (unsigned)t);
      if (t > 0 && tid < 32) {
        int p = (t - 1) & 1;
        sZi[tid] = 1.0f / (fZP[p*128 + tid*4] + fZP[p*128 + tid*4 + 1] +
                           fZP[p*128 + tid*4 + 2] + fZP[p*128 + tid*4 + 3]);
      }
      __syncthreads();
      for (int i = tid; i < 4096; i += 256) {           // q
        int b = i >> 7, k = i & 127;
        sX[b*648 + k] = f2bf(fQ2[((size_t)t*32 + b)*128 + k]);
      }
      for (int i = tid; i < 8192; i += 256) {           // attn(t-1)
        int b = i >> 8, d = i & 255; float v = 0.f;
        if (t > 0) {
          int p = (t - 1) & 1;
          const float* np = fNP + (size_t)p*32768 + (size_t)(b*4)*256 + d;
          v = (np[0] + np[256] + np[512] + np[768]) * sZi[b];
        }
        sX[b*648 + 128 + d] = f2bf(v);
      }
      for (int i = tid; i < 8192; i += 256) {           // h_a(t-1)
        int b = i >> 8, d = i & 255;
        float v = (t > 0) ? fHAS[((size_t)(t-1)*32 + b)*256 + d] : 0.f;
        sX[b*648 + 384 + d] = f2bf(v);
      }
      { int b = tid >> 3, ul = tid & 7;
        sHP[tid] = (t > 0) ? fHAS[((size_t)(t-1)*32 + b)*256 + j*8 + ul] : 0.f; }
      __syncthreads();
      { // GEMM [32x640]@[640x32]
        const int mt = wv >> 1, nt = wv & 1;
        f32x4 acc = {0.f, 0.f, 0.f, 0.f};
        const unsigned short* xr = sX + (size_t)(mt*16 + (lane&15))*648 + ((lane>>4)*8);
        const unsigned short* wh = sW + (size_t)(nt*16 + (lane&15))*648 + ((lane>>4)*8);
        const unsigned short* wl = wh + 32*648;
        for (int kt = 0; kt < 20; ++kt) {
          bf16x8 a  = *(const bf16x8*)(xr + kt*32);
          bf16x8 bh = *(const bf16x8*)(wh + kt*32);
          bf16x8 bl = *(const bf16x8*)(wl + kt*32);
          acc = __builtin_amdgcn_mfma_f32_16x16x32_bf16(a, bh, acc, 0, 0, 0);
          acc = __builtin_amdgcn_mfma_f32_16x16x32_bf16(a, bl, acc, 0, 0, 0);
        }
        int r0 = mt*16 + ((lane>>4)<<2), c = nt*16 + (lane&15);
        #pragma unroll
        for (int i2 = 0; i2 < 4; ++i2) sOut[(r0+i2)*36 + c] = acc[i2];
      }
      __syncthreads();
      { int b = tid >> 3, ul = tid & 7;
        float z = sigm(sOut[b*36 + ul] + sB[ul]);
        float r = sigm(sOut[b*36 + 8 + ul] + sB[8+ul]);
        float hh = ftanh(sOut[b*36 + 16 + ul] + sB[16+ul] + r*(sOut[b*36 + 24 + ul] + sB[24+ul]));
        float hn = z * sHP[tid] + (1.0f - z) * hh;
        sHN[tid] = hn;
        fHAS[((size_t)t*32 + b)*256 + j*8 + ul] = hn;
      }
      __syncthreads();
      { // Uh partial for this block's 8 units
        int dq = tid >> 5, b = tid & 31;
        float h0 = sHN[b*8+0], h1 = sHN[b*8+1], h2 = sHN[b*8+2], h3 = sHN[b*8+3];
        float h4 = sHN[b*8+4], h5 = sHN[b*8+5], h6 = sHN[b*8+6], h7 = sHN[b*8+7];
        float* dst = fUHP + ((size_t)j*32 + b)*256 + dq*32;
        #pragma unroll 4
        for (int dd = 0; dd < 32; ++dd) {
          int d = dq*32 + dd;
          dst[dd] = h0*sU[d] + h1*sU[256+d] + h2*sU[512+d] + h3*sU[768+d]
                  + h4*sU[1024+d] + h5*sU[1280+d] + h6*sU[1536+d] + h7*sU[1792+d];
        }
      }
      bump(cA);
    }
  } else if (bid < 160) {
    // ================= stage Bp: attention partials (50 enc rows) ==========
    const int idx = bid - 32, b = idx >> 2, q = idx & 3;
    float* sWV  = (float*)smem;            // [50][260]
    float* sMem = (float*)(smem + 52000);  // [50][260]
    float* sV   = (float*)(smem + 104000); // [256]
    float* sUh  = (float*)(smem + 105024); // [256]
    float* sE   = (float*)(smem + 106048); // [64]
    float* sZ   = (float*)(smem + 106304); // [1]
    for (int i = tid; i < 50*256; i += 256) {
      int r = i >> 8, d = i & 255;
      sWV[r*260 + d]  = fWV[((size_t)b*200 + q*50 + r)*256 + d];
      sMem[r*260 + d] = memg[((size_t)b*200 + q*50 + r)*256 + d];
    }
    sV[tid] = Vw[tid];
    __syncthreads();
    for (int t = 0; t < TDEC; ++t) {
      waitc(cA, 32u * (unsigned)(t + 1));
      if (t > 0) waitc(cC1, 32u * (unsigned)t);
      { float s = 0.f;
        #pragma unroll 4
        for (int j2 = 0; j2 < 32; ++j2) s += fUHP[((size_t)j2*32 + b)*256 + tid];
        sUh[tid] = s; }
      __syncthreads();
      { int r = tid >> 2, qd = tid & 3;
        float part = 0.f;
        if (r < 50) {
          const float* wvp = sWV + r*260 + qd*64;
          const float* uh = sUh + qd*64;
          const float* vv = sV + qd*64;
          #pragma unroll 8
          for (int i2 = 0; i2 < 64; ++i2) part += vv[i2] * ftanh(wvp[i2] + uh[i2]);
        }
        part += __shfl_down(part, 2, 4);
        part += __shfl_down(part, 1, 4);
        if (r < 50 && qd == 0) sE[r] = __expf(part);   // max-free: |score| <= ~13
      }
      __syncthreads();
      if (tid < 64) {
        float e = (tid < 50) ? sE[tid] : 0.f;
        #pragma unroll
        for (int off = 32; off; off >>= 1) e += __shfl_xor(e, off, 64);
        if (tid == 0) sZ[0] = e;
      }
      __syncthreads();
      { float acc = 0.f;
        #pragma unroll 2
        for (int r = 0; r < 50; ++r) acc += sE[r] * sMem[r*260 + tid];
        fNP[(size_t)(t & 1)*32768 + ((size_t)b*4 + q)*256 + tid] = acc; }
      if (tid == 0) fZP[(t & 1)*128 + b*4 + q] = sZ[0];
      bump(cB);
    }
  } else if (bid < 192) {
    // ================= stage C: proj + GRU1 (8 units) ======================
    const int j = bid - 160;
    unsigned short* sW1 = (unsigned short*)smem;            // [2][16][520]
    unsigned short* sW2 = (unsigned short*)(smem + 33280);  // [2][32][520]
    unsigned short* sX  = (unsigned short*)(smem + 99840);  // [32][520]
    float* sOut = (float*)(smem + 133120);                  // [32][36]
    float* sPJ  = (float*)(smem + 137728);                  // [32][8]
    float* sH1p = (float*)(smem + 138752);                  // [32][8]
    float* sB   = (float*)(smem + 139776);                  // [5][8]
    float* sZi  = (float*)(smem + 139968);                  // [32]
    {
      const uint4* s1 = (const uint4*)(img + IMGC1_OFF + (size_t)j*2*16*520);
      uint4* d1 = (uint4*)sW1;
      for (int i = tid; i < 33280/16; i += 256) d1[i] = s1[i];
      const uint4* s2 = (const uint4*)(img + IMGC2_OFF + (size_t)j*2*32*520);
      uint4* d2 = (uint4*)sW2;
      for (int i = tid; i < 66560/16; i += 256) d2[i] = s2[i];
      if (tid < 8) {
        int u = j*8 + tid;
        sB[tid]      = B1v[u]       + B1v[768 + u];
        sB[8 + tid]  = B1v[256 + u] + B1v[1024 + u];
        sB[16 + tid] = B1v[512 + u];
        sB[24 + tid] = B1v[1280 + u];
        sB[32 + tid] = pb[u];
      }
    }
    __syncthreads();
    for (int t = 0; t < TDEC; ++t) {
      waitc(cB, 128u * (unsigned)(t + 1));
      if (t > 0) waitc(cC2, 32u * (unsigned)t);
      if (t >= 2) waitc(cD, 32u * (unsigned)(t - 1));
      if (tid < 32) {
        int p = t & 1;
        sZi[tid] = 1.0f / (fZP[p*128 + tid*4] + fZP[p*128 + tid*4 + 1] +
                           fZP[p*128 + tid*4 + 2] + fZP[p*128 + tid*4 + 3]);
      }
      __syncthreads();
      for (int i = tid; i < 8192; i += 256) {           // attn(t)
        int b = i >> 8, d = i & 255;
        int p = t & 1;
        const float* np = fNP + (size_t)p*32768 + (size_t)(b*4)*256 + d;
        sX[b*520 + d] = f2bf((np[0] + np[256] + np[512] + np[768]) * sZi[b]);
      }
      for (int i = tid; i < 8192; i += 256) {           // h_a(t)
        int b = i >> 8, d = i & 255;
        sX[b*520 + 256 + d] = f2bf(fHAS[((size_t)t*32 + b)*256 + d]);
      }
      __syncthreads();
      if (wv < 2) { // GEMM proj: [32x512]@[512x16(8 valid)]
        const int mt = wv;
        f32x4 acc = {0.f, 0.f, 0.f, 0.f};
        const unsigned short* xr = sX + (size_t)(mt*16 + (lane&15))*520 + ((lane>>4)*8);
        const unsigned short* wh = sW1 + (size_t)(lane&15)*520 + ((lane>>4)*8);
        const unsigned short* wl = wh + 16*520;
        for (int kt = 0; kt < 16; ++kt) {
          bf16x8 a  = *(const bf16x8*)(xr + kt*32);
          bf16x8 bh = *(const bf16x8*)(wh + kt*32);
          bf16x8 bl = *(const bf16x8*)(wl + kt*32);
          acc = __builtin_amdgcn_mfma_f32_16x16x32_bf16(a, bh, acc, 0, 0, 0);
          acc = __builtin_amdgcn_mfma_f32_16x16x32_bf16(a, bl, acc, 0, 0, 0);
        }
        int r0 = mt*16 + ((lane>>4)<<2), c = lane & 15;
        #pragma unroll
        for (int i2 = 0; i2 < 4; ++i2) sOut[(r0+i2)*36 + c] = acc[i2];
      }
      __syncthreads();
      { int b = tid >> 3, ul = tid & 7;
        float pj = sOut[b*36 + ul] + sB[32 + ul];
        sPJ[tid] = pj;
        fPJ[(size_t)b*256 + j*8 + ul] = pj; }
      bump(cC1);
      waitc(cC1, 32u * (unsigned)(t + 1));
      for (int i = tid; i < 8192; i += 256) {           // proj(t) full
        int b = i >> 8, d = i & 255;
        sX[b*520 + d] = f2bf(fPJ[(size_t)b*256 + d]);
      }
      for (int i = tid; i < 8192; i += 256) {           // h1(t-1)
        int b = i >> 8, d = i & 255;
        sX[b*520 + 256 + d] = f2bf(fH1B[(size_t)(t & 1)*8192 + (size_t)b*256 + d]);
      }
      { int b = tid >> 3, ul = tid & 7;
        sH1p[tid] = fH1B[(size_t)(t & 1)*8192 + (size_t)b*256 + j*8 + ul]; }
      __syncthreads();
      { // GEMM GRU1
        const int mt = wv >> 1, nt = wv & 1;
        f32x4 acc = {0.f, 0.f, 0.f, 0.f};
        const unsigned short* xr = sX + (size_t)(mt*16 + (lane&15))*520 + ((lane>>4)*8);
        const unsigned short* wh = sW2 + (size_t)(nt*16 + (lane&15))*520 + ((lane>>4)*8);
        const unsigned short* wl = wh + 32*520;
        for (int kt = 0; kt < 16; ++kt) {
          bf16x8 a  = *(const bf16x8*)(xr + kt*32);
          bf16x8 bh = *(const bf16x8*)(wh + kt*32);
          bf16x8 bl = *(const bf16x8*)(wl + kt*32);
          acc = __builtin_amdgcn_mfma_f32_16x16x32_bf16(a, bh, acc, 0, 0, 0);
          acc = __builtin_amdgcn_mfma_f32_16x16x32_bf16(a, bl, acc, 0, 0, 0);
        }
        int r0 = mt*16 + ((lane>>4)<<2), c = nt*16 + (lane&15);
        #pragma unroll
        for (int i2 = 0; i2 < 4; ++i2) sOut[(r0+i2)*36 + c] = acc[i2];
      }
      __syncthreads();
      { int b = tid >> 3, ul = tid & 7;
        float z = sigm(sOut[b*36 + ul] + sB[ul]);
        float r = sigm(sOut[b*36 + 8 + ul] + sB[8+ul]);
        float hh = ftanh(sOut[b*36 + 16 + ul] + sB[16+ul] + r*(sOut[b*36 + 24 + ul] + sB[24+ul]));
        float hn = z * sH1p[tid] + (1.0f - z) * hh;
        fH1B[(size_t)((t+1) & 1)*8192 + (size_t)b*256 + j*8 + ul] = hn;
        fR1B[(size_t)(t & 1)*8192 + (size_t)b*256 + j*8 + ul] = sPJ[tid] + hn;
      }
      bump(cC2);
    }
  } else {
    // ================= stage D: GRU2 (8 units) =============================
    const int j = bid - 192;
    unsigned short* sW = (unsigned short*)smem;            // [2][32][520]
    unsigned short* sX = (unsigned short*)(smem + 66560);  // [32][520]
    float* sOut = (float*)(smem + 99840);                  // [32][36]
    float* sR1f = (float*)(smem + 104448);                 // [32][8]
    float* sH2p = (float*)(smem + 105472);                 // [32][8]
    float* sB   = (float*)(smem + 106496);                 // [4][8]
    {
      const uint4* s2 = (const uint4*)(img + IMGD_OFF + (size_t)j*2*32*520);
      uint4* d2 = (uint4*)sW;
      for (int i = tid; i < 66560/16; i += 256) d2[i] = s2[i];
      if (tid < 8) {
        int u = j*8 + tid;
        sB[tid]      = B2v[u]       + B2v[768 + u];
        sB[8 + tid]  = B2v[256 + u] + B2v[1024 + u];
        sB[16 + tid] = B2v[512 + u];
        sB[24 + tid] = B2v[1280 + u];
      }
    }
    __syncthreads();
    for (int t = 0; t < TDEC; ++t) {
      waitc(cC2, 32u * (unsigned)(t + 1));
      if (t > 0) waitc(cD, 32u * (unsigned)t);
      for (int i = tid; i < 8192; i += 256) {           // r1(t)
        int b = i >> 8, d = i & 255;
        sX[b*520 + d] = f2bf(fR1B[(size_t)(t & 1)*8192 + (size_t)b*256 + d]);
      }
      for (int i = tid; i < 8192; i += 256) {           // h2(t-1)
        int b = i >> 8, d = i & 255;
        sX[b*520 + 256 + d] = f2bf(fH2B[(size_t)(t & 1)*8192 + (size_t)b*256 + d]);
      }
      { int b = tid >> 3, ul = tid & 7;
        sR1f[tid] = fR1B[(size_t)(t & 1)*8192 + (size_t)b*256 + j*8 + ul];
        sH2p[tid] = fH2B[(size_t)(t & 1)*8192 + (size_t)b*256 + j*8 + ul]; }
      __syncthreads();
      { const int mt = wv >> 1, nt = wv & 1;
        f32x4 acc = {0.f, 0.f, 0.f, 0.f};
        const unsigned short* xr = sX + (size_t)(mt*16 + (lane&15))*520 + ((lane>>4)*8);
        const unsigned short* wh = sW + (size_t)(nt*16 + (lane&15))*520 + ((lane>>4)*8);
        const unsigned short* wl = wh + 32*520;
        for (int kt = 0; kt < 16; ++kt) {
          bf16x8 a  = *(const bf16x8*)(xr + kt*32);
          bf16x8 bh = *(const bf16x8*)(wh + kt*32);
          bf16x8 bl = *(const bf16x8*)(wl + kt*32);
          acc = __builtin_amdgcn_mfma_f32_16x16x32_bf16(a, bh, acc, 0, 0, 0);
          acc = __builtin_amdgcn_mfma_f32_16x16x32_bf16(a, bl, acc, 0, 0, 0);
        }
        int r0 = mt*16 + ((lane>>4)<<2), c = nt*16 + (lane&15);
        #pragma unroll
        for (int i2 = 0; i2 < 4; ++i2) sOut[(r0+i2)*36 + c] = acc[i2];
      }
      __syncthreads();
      { int b = tid >> 3, ul = tid & 7;
        float z = sigm(sOut[b*36 + ul] + sB[ul]);
        float r = sigm(sOut[b*36 + 8 + ul] + sB[8+ul]);
        float hh = ftanh(sOut[b*36 + 16 + ul] + sB[16+ul] + r*(sOut[b*36 + 24 + ul] + sB[24+ul]));
        float hn = z * sH2p[tid] + (1.0f - z) * hh;
        fH2B[(size_t)((t+1) & 1)*8192 + (size_t)b*256 + j*8 + ul] = hn;
        fR2S[((size_t)t*32 + b)*256 + j*8 + ul] = sR1f[tid] + hn;
      }
      bump(cD);
    }
  }
}

// ---------------------------------------------------------------------------
__global__ __launch_bounds__(256) void k_wv(
    const float* __restrict__ mem, const float* __restrict__ W, float* __restrict__ wv)
{
  const int tile = blockIdx.x, b = blockIdx.y;
  const int t0 = tile * 8, tid = threadIdx.x;
  __shared__ float rows[2048];
  for (int i = tid; i < 2048; i += 256) rows[i] = mem[((size_t)b*TENC + t0)*256 + i];
  __syncthreads();
  float acc[8] = {0,0,0,0,0,0,0,0};
  for (int k = 0; k < 256; ++k) {
    float w = W[(size_t)k*256 + tid];
    #pragma unroll
    for (int tt = 0; tt < 8; ++tt) acc[tt] += rows[tt*256 + k] * w;
  }
  #pragma unroll
  for (int tt = 0; tt < 8; ++tt) wv[((size_t)b*TENC + t0 + tt)*256 + tid] = acc[tt];
}

__global__ __launch_bounds__(256) void k_prenet(
    const float* __restrict__ x, const float* __restrict__ w1, const float* __restrict__ b1,
    const float* __restrict__ w2, const float* __restrict__ b2, float* __restrict__ q2)
{
  const int tile = blockIdx.x, b = blockIdx.y;
  const int t0 = tile * 4, tid = threadIdx.x;
  __shared__ float xr[320];
  __shared__ float q1[1024];
  for (int i = tid; i < 320; i += 256) {
    int tt = i / 80, k = i - tt*80;
    xr[i] = x[((size_t)b*TDEC + t0 + tt)*80 + k];
  }
  __syncthreads();
  {
    float a0 = 0.f, a1 = 0.f, a2 = 0.f, a3 = 0.f;
    for (int k = 0; k < 80; ++k) {
      float w = w1[(size_t)k*256 + tid];
      a0 += xr[k]*w; a1 += xr[80+k]*w; a2 += xr[160+k]*w; a3 += xr[240+k]*w;
    }
    float bb = b1[tid];
    q1[tid]       = fmaxf(a0 + bb, 0.f);
    q1[256 + tid] = fmaxf(a1 + bb, 0.f);
    q1[512 + tid] = fmaxf(a2 + bb, 0.f);
    q1[768 + tid] = fmaxf(a3 + bb, 0.f);
  }
  __syncthreads();
  {
    const int jj = tid & 127, tp = tid >> 7;
    float c0 = 0.f, c1 = 0.f;
    for (int k = 0; k < 256; ++k) {
      float w = w2[(size_t)k*128 + jj];
      c0 += q1[(2*tp)*256 + k] * w;
      c1 += q1[(2*tp + 1)*256 + k] * w;
    }
    float bb = b2[jj];
    q2[(((size_t)t0 + 2*tp)*32 + b)*128 + jj]     = fmaxf(c0 + bb, 0.f);
    q2[(((size_t)t0 + 2*tp + 1)*32 + b)*128 + jj] = fmaxf(c1 + bb, 0.f);
  }
}

__global__ __launch_bounds__(128) void k_out(
    const float* __restrict__ r2, const float* __restrict__ wo,
    const float* __restrict__ bo, float* __restrict__ out)
{
  const int tb = blockIdx.x;
  const int t = tb >> 5, b = tb & 31, tid = threadIdx.x;
  __shared__ float row[256];
  for (int i = tid; i < 256; i += 128) row[i] = r2[(size_t)tb*256 + i];
  __syncthreads();
  if (tid < 80) {
    float acc = bo[tid];
    #pragma unroll 4
    for (int k = 0; k < 256; ++k) acc += row[k] * wo[(size_t)k*80 + tid];
    out[((size_t)b*TDEC + t)*80 + tid] = acc;
  }
}

// ---------------------------------------------------------------------------
extern "C" void kernel_launch(void* const* d_in, const int* in_sizes, int n_in,
                              void* d_out, int out_size, void* d_ws, size_t ws_size,
                              hipStream_t stream)
{
  const float* mem = (const float*)d_in[0];
  const float* dec = (const float*)d_in[1];
  const float* w1  = (const float*)d_in[2];
  const float* b1  = (const float*)d_in[3];
  const float* w2  = (const float*)d_in[4];
  const float* b2  = (const float*)d_in[5];
  const float* aK  = (const float*)d_in[6];
  const float* aRK = (const float*)d_in[7];
  const float* aB  = (const float*)d_in[8];
  const float* W   = (const float*)d_in[9];
  const float* U   = (const float*)d_in[10];
  const float* V   = (const float*)d_in[11];
  const float* Wp  = (const float*)d_in[12];
  const float* pb  = (const float*)d_in[13];
  const float* K1  = (const float*)d_in[14];
  const float* RK1 = (const float*)d_in[15];
  const float* B1v = (const float*)d_in[16];
  const float* K2  = (const float*)d_in[17];
  const float* RK2 = (const float*)d_in[18];
  const float* B2v = (const float*)d_in[19];
  const float* Wo  = (const float*)d_in[20];
  const float* bo  = (const float*)d_in[21];
  float* ws  = (float*)d_ws;
  float* out = (float*)d_out;

  hipMemsetAsync(ws, 0, (size_t)ZERO_FLOATS * sizeof(float), stream);
  k_prep<<<dim3(2592, 4), 256, 0, stream>>>(aK, aRK, Wp, K1, RK1, K2, RK2,
                                            (unsigned short*)(ws + O_IMG));
  k_wv<<<dim3(25, 32), 256, 0, stream>>>(mem, W, ws + O_WV);
  k_prenet<<<dim3(50, 32), 256, 0, stream>>>(dec, w1, b1, w2, b2, ws + O_Q2);
  k_scan5<<<224, 256, 0, stream>>>(mem, aB, U, V, pb, B1v, B2v, ws);
  k_out<<<6400, 128, 0, stream>>>(ws + O_R2S, Wo, bo, out);
}

// Round 6
// 7125.403 us; speedup vs baseline: 16.3777x; 1.2387x over previous
//
#include <hip/hip_runtime.h>
#include <math.h>

// ---------------------------------------------------------------------------
// Tacotron decoder scan, MI355X. Unit-split MFMA pipeline, zero grid barriers,
// per-block flag signaling (no atomic RMW storms).
// 224 blocks: A(32)=attn-GRU, Bp(128)=Bahdanau partials, C(32)=proj+GRU1,
// D(32)=GRU2. Weights as split-bf16 images, LDS-persistent per block.
// ---------------------------------------------------------------------------

#define TENC 200
#define TDEC 200

typedef short bf16x8 __attribute__((ext_vector_type(8)));
typedef float f32x4  __attribute__((ext_vector_type(4)));

// ---- ws float offsets -----------------------------------------------------
// flags: 256 slots x 32 uints (128B line each) = 8192 floats
//   A: 0..31, Bp: 32..159, C1: 160..191, C2: 192..223, D: 224..255
#define O_H1B   8192                    // [2][32][256] h1 parity
#define O_H2B   (O_H1B + 16384)
#define O_R1B   (O_H2B + 16384)
#define ZERO_FLOATS (O_R1B + 16384)     // 57344
#define O_HAS   57344                   // [200][32][256] h_a stream
#define O_UHP   (O_HAS + 200*32*256)    // [32][32][256] Uh partials
#define O_NP    (O_UHP + 32*32*256)     // [2][128][256] context partials
#define O_ZP    (O_NP + 2*128*256)      // [2][128]
#define O_PJ    (O_ZP + 256)            // [32][256] proj
#define O_Q2    (O_PJ + 8192)           // [200][32][128] prenet out
#define O_WV    (O_Q2 + 200*32*128)     // [32][200][256] memory@W
#define O_R2S   (O_WV + 32*200*256)     // [200][32][256] r2 stream
#define O_IMG   (O_R2S + 200*32*256)    // bf16 weight images (ushort*)

// image offsets in ushorts
#define IMGA_OFF  0u                    // [32][2][32][648]
#define IMGC1_OFF 1327104u              // [32][2][16][520]
#define IMGC2_OFF 1859584u              // [32][2][32][520]
#define IMGD_OFF  2924544u              // [32][2][32][520]

__device__ __forceinline__ float sigm(float x)  { return 1.0f / (1.0f + __expf(-x)); }
__device__ __forceinline__ float ftanh(float x) { return 1.0f - 2.0f / (1.0f + __expf(2.0f * x)); }

__device__ __forceinline__ unsigned short f2bf(float f) {
  union { float f; unsigned u; } v; v.f = f;
  return (unsigned short)((v.u + 0x7FFFu + ((v.u >> 16) & 1u)) >> 16);
}
__device__ __forceinline__ float bf2f(unsigned short h) {
  union { unsigned u; float f; } v; v.u = ((unsigned)h) << 16; return v.f;
}

// parallel poll: each active thread watches one producer flag; exit when all
// satisfied; then an ACQUIRE fence on every thread (cache invalidate).
__device__ __forceinline__ void pollwait(const unsigned* p, unsigned tgt, bool act) {
  for (;;) {
    bool ok = true;
    if (act) ok = (__hip_atomic_load(p, __ATOMIC_RELAXED, __HIP_MEMORY_SCOPE_AGENT) >= tgt);
    if (__syncthreads_and((int)ok)) break;
    __builtin_amdgcn_s_sleep(2);
  }
  __builtin_amdgcn_fence(__ATOMIC_ACQUIRE, "agent");
}
// publish: barrier (drain block stores), tid0 RELEASE fence + plain flag store.
__device__ __forceinline__ void set_flag(unsigned* f, unsigned v) {
  __syncthreads();
  if (threadIdx.x == 0) {
    __builtin_amdgcn_fence(__ATOMIC_RELEASE, "agent");
    __hip_atomic_store(f, v, __ATOMIC_RELAXED, __HIP_MEMORY_SCOPE_AGENT);
  }
}

// ---------------------------------------------------------------------------
// k_prep: build split-bf16 weight images. y: 0=A,1=C1,2=C2,3=D
__global__ __launch_bounds__(256) void k_prep(
    const float* __restrict__ aK, const float* __restrict__ aRK,
    const float* __restrict__ Wp,
    const float* __restrict__ K1, const float* __restrict__ RK1,
    const float* __restrict__ K2, const float* __restrict__ RK2,
    unsigned short* __restrict__ img)
{
  int e = blockIdx.x * 256 + threadIdx.x;
  int id = blockIdx.y;
  float w = 0.f; size_t oh = 0, ol = 0;
  if (id == 0) {
    if (e >= 32*32*648) return;
    int k = e % 648, n = (e / 648) & 31, blk = e / (648*32);
    int u = blk*8 + (n & 7), g = n >> 3;
    if (k < 384) {
      w = (g==0) ? aK[(size_t)k*768+u] : (g==1) ? aK[(size_t)k*768+256+u]
        : (g==2) ? aK[(size_t)k*768+512+u] : 0.f;
    } else if (k < 640) {
      int kk = k - 384;
      w = (g==0) ? aRK[(size_t)kk*768+u] : (g==1) ? aRK[(size_t)kk*768+256+u]
        : (g==3) ? aRK[(size_t)kk*768+512+u] : 0.f;
    }
    size_t base = IMGA_OFF + (size_t)blk*2*32*648;
    oh = base + (size_t)n*648 + k; ol = oh + 32*648;
  } else if (id == 1) {
    if (e >= 32*16*520) return;
    int k = e % 520, n = (e / 520) & 15, blk = e / (520*16);
    if (n < 8 && k < 512) w = Wp[(size_t)k*256 + blk*8 + n];
    size_t base = IMGC1_OFF + (size_t)blk*2*16*520;
    oh = base + (size_t)n*520 + k; ol = oh + 16*520;
  } else {
    if (e >= 32*32*520) return;
    int k = e % 520, n = (e / 520) & 31, blk = e / (520*32);
    int u = blk*8 + (n & 7), g = n >> 3;
    const float* Kx = (id == 2) ? K1 : K2;
    const float* Rx = (id == 2) ? RK1 : RK2;
    if (k < 256) {
      w = (g==0) ? Kx[(size_t)k*768+u] : (g==1) ? Kx[(size_t)k*768+256+u]
        : (g==2) ? Kx[(size_t)k*768+512+u] : 0.f;
    } else if (k < 512) {
      int kk = k - 256;
      w = (g==0) ? Rx[(size_t)kk*768+u] : (g==1) ? Rx[(size_t)kk*768+256+u]
        : (g==3) ? Rx[(size_t)kk*768+512+u] : 0.f;
    }
    size_t base = ((id == 2) ? IMGC2_OFF : IMGD_OFF) + (size_t)blk*2*32*520;
    oh = base + (size_t)n*520 + k; ol = oh + 32*520;
  }
  unsigned short hi = f2bf(w);
  unsigned short lo = f2bf(w - bf2f(hi));
  img[oh] = hi; img[ol] = lo;
}

// ---------------------------------------------------------------------------
__global__ __launch_bounds__(256, 1) void k_scan6(
    const float* __restrict__ memg,
    const float* __restrict__ aB, const float* __restrict__ Uw,
    const float* __restrict__ Vw, const float* __restrict__ pb,
    const float* __restrict__ B1v, const float* __restrict__ B2v,
    float* __restrict__ ws)
{
  const int tid = threadIdx.x, bid = blockIdx.x;
  const int lane = tid & 63, wv = tid >> 6;
  unsigned* fl = (unsigned*)ws;
  float* fH1B = ws + O_H1B;  float* fH2B = ws + O_H2B;  float* fR1B = ws + O_R1B;
  float* fHAS = ws + O_HAS;  float* fUHP = ws + O_UHP;
  float* fNP  = ws + O_NP;   float* fZP  = ws + O_ZP;   float* fPJ = ws + O_PJ;
  float* fQ2  = ws + O_Q2;   float* fWV  = ws + O_WV;   float* fR2S = ws + O_R2S;
  const unsigned short* img = (const unsigned short*)(ws + O_IMG);

  __shared__ __align__(16) char smem[140544];

  if (bid < 32) {
    // ================= stage A: attn-GRU (8 units) + Uh partials ===========
    const int j = bid;
    unsigned* myflag = fl + (0 + j) * 32;
    unsigned short* sW = (unsigned short*)smem;            // [2][32][648]
    unsigned short* sX = (unsigned short*)(smem + 82944);  // [32][648]
    float* sU  = (float*)(smem + 124416);                  // [8][256]
    float* sOut= (float*)(smem + 132608);                  // [32][36]
    float* sHN = (float*)(smem + 137216);                  // [32][8]
    float* sHP = (float*)(smem + 138240);                  // [32][8]
    float* sB  = (float*)(smem + 139264);                  // [4][8]
    float* sZi = (float*)(smem + 139392);                  // [32]
    {
      const uint4* src = (const uint4*)(img + IMGA_OFF + (size_t)j*2*32*648);
      uint4* dst = (uint4*)sW;
      for (int i = tid; i < 82944/16; i += 256) dst[i] = src[i];
      for (int i = tid; i < 2048; i += 256)
        sU[i] = Uw[(size_t)(j*8 + (i >> 8))*256 + (i & 255)];
      if (tid < 8) {
        int u = j*8 + tid;
        sB[tid]      = aB[u]       + aB[768 + u];
        sB[8 + tid]  = aB[256 + u] + aB[1024 + u];
        sB[16 + tid] = aB[512 + u];
        sB[24 + tid] = aB[1280 + u];
      }
    }
    __syncthreads();
    for (int t = 0; t < TDEC; ++t) {
      for (int i = tid; i < 4096; i += 256) {           // q (no dependency)
        int b = i >> 7, k = i & 127;
        sX[b*648 + k] = f2bf(fQ2[((size_t)t*32 + b)*128 + k]);
      }
      // wait: all 128 Bp finished step t-1
      pollwait(fl + (32 + (tid & 127))*32, (unsigned)t, (t > 0) && (tid < 128));
      if (t > 0 && tid < 32) {
        int p = (t - 1) & 1;
        sZi[tid] = 1.0f / (fZP[p*128 + tid*4] + fZP[p*128 + tid*4 + 1] +
                           fZP[p*128 + tid*4 + 2] + fZP[p*128 + tid*4 + 3]);
      }
      __syncthreads();
      for (int i = tid; i < 8192; i += 256) {           // attn(t-1)
        int b = i >> 8, d = i & 255; float v = 0.f;
        if (t > 0) {
          int p = (t - 1) & 1;
          const float* np = fNP + (size_t)p*32768 + (size_t)(b*4)*256 + d;
          v = (np[0] + np[256] + np[512] + np[768]) * sZi[b];
        }
        sX[b*648 + 128 + d] = f2bf(v);
      }
      for (int i = tid; i < 8192; i += 256) {           // h_a(t-1)
        int b = i >> 8, d = i & 255;
        float v = (t > 0) ? fHAS[((size_t)(t-1)*32 + b)*256 + d] : 0.f;
        sX[b*648 + 384 + d] = f2bf(v);
      }
      { int b = tid >> 3, ul = tid & 7;
        sHP[tid] = (t > 0) ? fHAS[((size_t)(t-1)*32 + b)*256 + j*8 + ul] : 0.f; }
      __syncthreads();
      { // GEMM [32x640]@[640x32]
        const int mt = wv >> 1, nt = wv & 1;
        f32x4 acc = {0.f, 0.f, 0.f, 0.f};
        const unsigned short* xr = sX + (size_t)(mt*16 + (lane&15))*648 + ((lane>>4)*8);
        const unsigned short* wh = sW + (size_t)(nt*16 + (lane&15))*648 + ((lane>>4)*8);
        const unsigned short* wl = wh + 32*648;
        for (int kt = 0; kt < 20; ++kt) {
          bf16x8 a  = *(const bf16x8*)(xr + kt*32);
          bf16x8 bh = *(const bf16x8*)(wh + kt*32);
          bf16x8 bl = *(const bf16x8*)(wl + kt*32);
          acc = __builtin_amdgcn_mfma_f32_16x16x32_bf16(a, bh, acc, 0, 0, 0);
          acc = __builtin_amdgcn_mfma_f32_16x16x32_bf16(a, bl, acc, 0, 0, 0);
        }
        int r0 = mt*16 + ((lane>>4)<<2), c = nt*16 + (lane&15);
        #pragma unroll
        for (int i2 = 0; i2 < 4; ++i2) sOut[(r0+i2)*36 + c] = acc[i2];
      }
      __syncthreads();
      { int b = tid >> 3, ul = tid & 7;
        float z = sigm(sOut[b*36 + ul] + sB[ul]);
        float r = sigm(sOut[b*36 + 8 + ul] + sB[8+ul]);
        float hh = ftanh(sOut[b*36 + 16 + ul] + sB[16+ul] + r*(sOut[b*36 + 24 + ul] + sB[24+ul]));
        float hn = z * sHP[tid] + (1.0f - z) * hh;
        sHN[tid] = hn;
        fHAS[((size_t)t*32 + b)*256 + j*8 + ul] = hn;
      }
      __syncthreads();
      { // Uh partial for this block's 8 units
        int dq = tid >> 5, b = tid & 31;
        float h0 = sHN[b*8+0], h1 = sHN[b*8+1], h2 = sHN[b*8+2], h3 = sHN[b*8+3];
        float h4 = sHN[b*8+4], h5 = sHN[b*8+5], h6 = sHN[b*8+6], h7 = sHN[b*8+7];
        float* dst = fUHP + ((size_t)j*32 + b)*256 + dq*32;
        #pragma unroll 4
        for (int dd = 0; dd < 32; ++dd) {
          int d = dq*32 + dd;
          dst[dd] = h0*sU[d] + h1*sU[256+d] + h2*sU[512+d] + h3*sU[768+d]
                  + h4*sU[1024+d] + h5*sU[1280+d] + h6*sU[1536+d] + h7*sU[1792+d];
        }
      }
      set_flag(myflag, (unsigned)(t + 1));
    }
  } else if (bid < 160) {
    // ================= stage Bp: attention partials (50 enc rows) ==========
    const int idx = bid - 32, b = idx >> 2, q = idx & 3;
    unsigned* myflag = fl + (32 + idx) * 32;
    float* sWV  = (float*)smem;            // [50][260]
    float* sMem = (float*)(smem + 52000);  // [50][260]
    float* sV   = (float*)(smem + 104000); // [256]
    float* sUh  = (float*)(smem + 105024); // [256]
    float* sE   = (float*)(smem + 106048); // [64]
    float* sZ   = (float*)(smem + 106304); // [1]
    for (int i = tid; i < 50*256; i += 256) {
      int r = i >> 8, d = i & 255;
      sWV[r*260 + d]  = fWV[((size_t)b*200 + q*50 + r)*256 + d];
      sMem[r*260 + d] = memg[((size_t)b*200 + q*50 + r)*256 + d];
    }
    sV[tid] = Vw[tid];
    __syncthreads();
    for (int t = 0; t < TDEC; ++t) {
      { // wait: A(t) done (32 flags >= t+1); C1 >= t (fNP parity safety)
        const unsigned* p; unsigned tg; bool act;
        if (tid < 32)      { p = fl + tid*32;               tg = (unsigned)(t+1); act = true; }
        else if (tid < 64) { p = fl + (160 + tid - 32)*32;  tg = (unsigned)t;     act = (t > 0); }
        else               { p = fl;                        tg = 0u;              act = false; }
        pollwait(p, tg, act);
      }
      { float s = 0.f;
        #pragma unroll 4
        for (int j2 = 0; j2 < 32; ++j2) s += fUHP[((size_t)j2*32 + b)*256 + tid];
        sUh[tid] = s; }
      __syncthreads();
      { int r = tid >> 2, qd = tid & 3;
        float part = 0.f;
        if (r < 50) {
          const float* wvp = sWV + r*260 + qd*64;
          const float* uh = sUh + qd*64;
          const float* vv = sV + qd*64;
          #pragma unroll 8
          for (int i2 = 0; i2 < 64; ++i2) part += vv[i2] * ftanh(wvp[i2] + uh[i2]);
        }
        part += __shfl_down(part, 2, 4);
        part += __shfl_down(part, 1, 4);
        if (r < 50 && qd == 0) sE[r] = __expf(part);   // max-free: |score| bounded
      }
      __syncthreads();
      if (tid < 64) {
        float e = (tid < 50) ? sE[tid] : 0.f;
        #pragma unroll
        for (int off = 32; off; off >>= 1) e += __shfl_xor(e, off, 64);
        if (tid == 0) sZ[0] = e;
      }
      __syncthreads();
      { float acc = 0.f;
        #pragma unroll 2
        for (int r = 0; r < 50; ++r) acc += sE[r] * sMem[r*260 + tid];
        fNP[(size_t)(t & 1)*32768 + ((size_t)b*4 + q)*256 + tid] = acc; }
      if (tid == 0) fZP[(t & 1)*128 + b*4 + q] = sZ[0];
      set_flag(myflag, (unsigned)(t + 1));
    }
  } else if (bid < 192) {
    // ================= stage C: proj + GRU1 (8 units) ======================
    const int j = bid - 160;
    unsigned* flagC1 = fl + (160 + j) * 32;
    unsigned* flagC2 = fl + (192 + j) * 32;
    unsigned short* sW1 = (unsigned short*)smem;            // [2][16][520]
    unsigned short* sW2 = (unsigned short*)(smem + 33280);  // [2][32][520]
    unsigned short* sX  = (unsigned short*)(smem + 99840);  // [32][520]
    float* sOut = (float*)(smem + 133120);                  // [32][36]
    float* sPJ  = (float*)(smem + 137728);                  // [32][8]
    float* sH1p = (float*)(smem + 138752);                  // [32][8]
    float* sB   = (float*)(smem + 139776);                  // [5][8]
    float* sZi  = (float*)(smem + 139968);                  // [32]
    {
      const uint4* s1 = (const uint4*)(img + IMGC1_OFF + (size_t)j*2*16*520);
      uint4* d1 = (uint4*)sW1;
      for (int i = tid; i < 33280/16; i += 256) d1[i] = s1[i];
      const uint4* s2 = (const uint4*)(img + IMGC2_OFF + (size_t)j*2*32*520);
      uint4* d2 = (uint4*)sW2;
      for (int i = tid; i < 66560/16; i += 256) d2[i] = s2[i];
      if (tid < 8) {
        int u = j*8 + tid;
        sB[tid]      = B1v[u]       + B1v[768 + u];
        sB[8 + tid]  = B1v[256 + u] + B1v[1024 + u];
        sB[16 + tid] = B1v[512 + u];
        sB[24 + tid] = B1v[1280 + u];
        sB[32 + tid] = pb[u];
      }
    }
    __syncthreads();
    for (int t = 0; t < TDEC; ++t) {
      { // wait: Bp(t) done; C2 >= t (fPJ/h1 safety); D >= t-1 (r1 parity safety)
        const unsigned* p; unsigned tg; bool act;
        if (tid < 128)      { p = fl + (32 + tid)*32;         tg = (unsigned)(t+1); act = true; }
        else if (tid < 160) { p = fl + (192 + tid - 128)*32;  tg = (unsigned)t;     act = (t > 0); }
        else if (tid < 192) { p = fl + (224 + tid - 160)*32;  tg = (unsigned)(t-1); act = (t >= 2); }
        else                { p = fl;                         tg = 0u;              act = false; }
        pollwait(p, tg, act);
      }
      if (tid < 32) {
        int p = t & 1;
        sZi[tid] = 1.0f / (fZP[p*128 + tid*4] + fZP[p*128 + tid*4 + 1] +
                           fZP[p*128 + tid*4 + 2] + fZP[p*128 + tid*4 + 3]);
      }
      __syncthreads();
      for (int i = tid; i < 8192; i += 256) {           // attn(t)
        int b = i >> 8, d = i & 255;
        int p = t & 1;
        const float* np = fNP + (size_t)p*32768 + (size_t)(b*4)*256 + d;
        sX[b*520 + d] = f2bf((np[0] + np[256] + np[512] + np[768]) * sZi[b]);
      }
      for (int i = tid; i < 8192; i += 256) {           // h_a(t)
        int b = i >> 8, d = i & 255;
        sX[b*520 + 256 + d] = f2bf(fHAS[((size_t)t*32 + b)*256 + d]);
      }
      __syncthreads();
      if (wv < 2) { // GEMM proj: [32x512]@[512x16(8 valid)]
        const int mt = wv;
        f32x4 acc = {0.f, 0.f, 0.f, 0.f};
        const unsigned short* xr = sX + (size_t)(mt*16 + (lane&15))*520 + ((lane>>4)*8);
        const unsigned short* wh = sW1 + (size_t)(lane&15)*520 + ((lane>>4)*8);
        const unsigned short* wl = wh + 16*520;
        for (int kt = 0; kt < 16; ++kt) {
          bf16x8 a  = *(const bf16x8*)(xr + kt*32);
          bf16x8 bh = *(const bf16x8*)(wh + kt*32);
          bf16x8 bl = *(const bf16x8*)(wl + kt*32);
          acc = __builtin_amdgcn_mfma_f32_16x16x32_bf16(a, bh, acc, 0, 0, 0);
          acc = __builtin_amdgcn_mfma_f32_16x16x32_bf16(a, bl, acc, 0, 0, 0);
        }
        int r0 = mt*16 + ((lane>>4)<<2), c = lane & 15;
        #pragma unroll
        for (int i2 = 0; i2 < 4; ++i2) sOut[(r0+i2)*36 + c] = acc[i2];
      }
      __syncthreads();
      { int b = tid >> 3, ul = tid & 7;
        float pj = sOut[b*36 + ul] + sB[32 + ul];
        sPJ[tid] = pj;
        fPJ[(size_t)b*256 + j*8 + ul] = pj; }
      set_flag(flagC1, (unsigned)(t + 1));
      pollwait(fl + (160 + (tid & 31))*32, (unsigned)(t + 1), tid < 32);
      for (int i = tid; i < 8192; i += 256) {           // proj(t) full
        int b = i >> 8, d = i & 255;
        sX[b*520 + d] = f2bf(fPJ[(size_t)b*256 + d]);
      }
      for (int i = tid; i < 8192; i += 256) {           // h1(t-1)
        int b = i >> 8, d = i & 255;
        sX[b*520 + 256 + d] = f2bf(fH1B[(size_t)(t & 1)*8192 + (size_t)b*256 + d]);
      }
      { int b = tid >> 3, ul = tid & 7;
        sH1p[tid] = fH1B[(size_t)(t & 1)*8192 + (size_t)b*256 + j*8 + ul]; }
      __syncthreads();
      { // GEMM GRU1
        const int mt = wv >> 1, nt = wv & 1;
        f32x4 acc = {0.f, 0.f, 0.f, 0.f};
        const unsigned short* xr = sX + (size_t)(mt*16 + (lane&15))*520 + ((lane>>4)*8);
        const unsigned short* wh = sW2 + (size_t)(nt*16 + (lane&15))*520 + ((lane>>4)*8);
        const unsigned short* wl = wh + 32*520;
        for (int kt = 0; kt < 16; ++kt) {
          bf16x8 a  = *(const bf16x8*)(xr + kt*32);
          bf16x8 bh = *(const bf16x8*)(wh + kt*32);
          bf16x8 bl = *(const bf16x8*)(wl + kt*32);
          acc = __builtin_amdgcn_mfma_f32_16x16x32_bf16(a, bh, acc, 0, 0, 0);
          acc = __builtin_amdgcn_mfma_f32_16x16x32_bf16(a, bl, acc, 0, 0, 0);
        }
        int r0 = mt*16 + ((lane>>4)<<2), c = nt*16 + (lane&15);
        #pragma unroll
        for (int i2 = 0; i2 < 4; ++i2) sOut[(r0+i2)*36 + c] = acc[i2];
      }
      __syncthreads();
      { int b = tid >> 3, ul = tid & 7;
        float z = sigm(sOut[b*36 + ul] + sB[ul]);
        float r = sigm(sOut[b*36 + 8 + ul] + sB[8+ul]);
        float hh = ftanh(sOut[b*36 + 16 + ul] + sB[16+ul] + r*(sOut[b*36 + 24 + ul] + sB[24+ul]));
        float hn = z * sH1p[tid] + (1.0f - z) * hh;
        fH1B[(size_t)((t+1) & 1)*8192 + (size_t)b*256 + j*8 + ul] = hn;
        fR1B[(size_t)(t & 1)*8192 + (size_t)b*256 + j*8 + ul] = sPJ[tid] + hn;
      }
      set_flag(flagC2, (unsigned)(t + 1));
    }
  } else {
    // ================= stage D: GRU2 (8 units) =============================
    const int j = bid - 192;
    unsigned* myflag = fl + (224 + j) * 32;
    unsigned short* sW = (unsigned short*)smem;            // [2][32][520]
    unsigned short* sX = (unsigned short*)(smem + 66560);  // [32][520]
    float* sOut = (float*)(smem + 99840);                  // [32][36]
    float* sR1f = (float*)(smem + 104448);                 // [32][8]
    float* sH2p = (float*)(smem + 105472);                 // [32][8]
    float* sB   = (float*)(smem + 106496);                 // [4][8]
    {
      const uint4* s2 = (const uint4*)(img + IMGD_OFF + (size_t)j*2*32*520);
      uint4* d2 = (uint4*)sW;
      for (int i = tid; i < 66560/16; i += 256) d2[i] = s2[i];
      if (tid < 8) {
        int u = j*8 + tid;
        sB[tid]      = B2v[u]       + B2v[768 + u];
        sB[8 + tid]  = B2v[256 + u] + B2v[1024 + u];
        sB[16 + tid] = B2v[512 + u];
        sB[24 + tid] = B2v[1280 + u];
      }
    }
    __syncthreads();
    for (int t = 0; t < TDEC; ++t) {
      { // wait: C2 >= t+1; D >= t (h2 parity safety)
        const unsigned* p; unsigned tg; bool act;
        if (tid < 32)      { p = fl + (192 + tid)*32;       tg = (unsigned)(t+1); act = true; }
        else if (tid < 64) { p = fl + (224 + tid - 32)*32;  tg = (unsigned)t;     act = (t > 0); }
        else               { p = fl;                        tg = 0u;              act = false; }
        pollwait(p, tg, act);
      }
      for (int i = tid; i < 8192; i += 256) {           // r1(t)
        int b = i >> 8, d = i & 255;
        sX[b*520 + d] = f2bf(fR1B[(size_t)(t & 1)*8192 + (size_t)b*256 + d]);
      }
      for (int i = tid; i < 8192; i += 256) {           // h2(t-1)
        int b = i >> 8, d = i & 255;
        sX[b*520 + 256 + d] = f2bf(fH2B[(size_t)(t & 1)*8192 + (size_t)b*256 + d]);
      }
      { int b = tid >> 3, ul = tid & 7;
        sR1f[tid] = fR1B[(size_t)(t & 1)*8192 + (size_t)b*256 + j*8 + ul];
        sH2p[tid] = fH2B[(size_t)(t & 1)*8192 + (size_t)b*256 + j*8 + ul]; }
      __syncthreads();
      { const int mt = wv >> 1, nt = wv & 1;
        f32x4 acc = {0.f, 0.f, 0.f, 0.f};
        const unsigned short* xr = sX + (size_t)(mt*16 + (lane&15))*520 + ((lane>>4)*8);
        const unsigned short* wh = sW + (size_t)(nt*16 + (lane&15))*520 + ((lane>>4)*8);
        const unsigned short* wl = wh + 32*520;
        for (int kt = 0; kt < 16; ++kt) {
          bf16x8 a  = *(const bf16x8*)(xr + kt*32);
          bf16x8 bh = *(const bf16x8*)(wh + kt*32);
          bf16x8 bl = *(const bf16x8*)(wl + kt*32);
          acc = __builtin_amdgcn_mfma_f32_16x16x32_bf16(a, bh, acc, 0, 0, 0);
          acc = __builtin_amdgcn_mfma_f32_16x16x32_bf16(a, bl, acc, 0, 0, 0);
        }
        int r0 = mt*16 + ((lane>>4)<<2), c = nt*16 + (lane&15);
        #pragma unroll
        for (int i2 = 0; i2 < 4; ++i2) sOut[(r0+i2)*36 + c] = acc[i2];
      }
      __syncthreads();
      { int b = tid >> 3, ul = tid & 7;
        float z = sigm(sOut[b*36 + ul] + sB[ul]);
        float r = sigm(sOut[b*36 + 8 + ul] + sB[8+ul]);
        float hh = ftanh(sOut[b*36 + 16 + ul] + sB[16+ul] + r*(sOut[b*36 + 24 + ul] + sB[24+ul]));
        float hn = z * sH2p[tid] + (1.0f - z) * hh;
        fH2B[(size_t)((t+1) & 1)*8192 + (size_t)b*256 + j*8 + ul] = hn;
        fR2S[((size_t)t*32 + b)*256 + j*8 + ul] = sR1f[tid] + hn;
      }
      set_flag(myflag, (unsigned)(t + 1));
    }
  }
}

// ---------------------------------------------------------------------------
__global__ __launch_bounds__(256) void k_wv(
    const float* __restrict__ mem, const float* __restrict__ W, float* __restrict__ wv)
{
  const int tile = blockIdx.x, b = blockIdx.y;
  const int t0 = tile * 8, tid = threadIdx.x;
  __shared__ float rows[2048];
  for (int i = tid; i < 2048; i += 256) rows[i] = mem[((size_t)b*TENC + t0)*256 + i];
  __syncthreads();
  float acc[8] = {0,0,0,0,0,0,0,0};
  for (int k = 0; k < 256; ++k) {
    float w = W[(size_t)k*256 + tid];
    #pragma unroll
    for (int tt = 0; tt < 8; ++tt) acc[tt] += rows[tt*256 + k] * w;
  }
  #pragma unroll
  for (int tt = 0; tt < 8; ++tt) wv[((size_t)b*TENC + t0 + tt)*256 + tid] = acc[tt];
}

__global__ __launch_bounds__(256) void k_prenet(
    const float* __restrict__ x, const float* __restrict__ w1, const float* __restrict__ b1,
    const float* __restrict__ w2, const float* __restrict__ b2, float* __restrict__ q2)
{
  const int tile = blockIdx.x, b = blockIdx.y;
  const int t0 = tile * 4, tid = threadIdx.x;
  __shared__ float xr[320];
  __shared__ float q1[1024];
  for (int i = tid; i < 320; i += 256) {
    int tt = i / 80, k = i - tt*80;
    xr[i] = x[((size_t)b*TDEC + t0 + tt)*80 + k];
  }
  __syncthreads();
  {
    float a0 = 0.f, a1 = 0.f, a2 = 0.f, a3 = 0.f;
    for (int k = 0; k < 80; ++k) {
      float w = w1[(size_t)k*256 + tid];
      a0 += xr[k]*w; a1 += xr[80+k]*w; a2 += xr[160+k]*w; a3 += xr[240+k]*w;
    }
    float bb = b1[tid];
    q1[tid]       = fmaxf(a0 + bb, 0.f);
    q1[256 + tid] = fmaxf(a1 + bb, 0.f);
    q1[512 + tid] = fmaxf(a2 + bb, 0.f);
    q1[768 + tid] = fmaxf(a3 + bb, 0.f);
  }
  __syncthreads();
  {
    const int jj = tid & 127, tp = tid >> 7;
    float c0 = 0.f, c1 = 0.f;
    for (int k = 0; k < 256; ++k) {
      float w = w2[(size_t)k*128 + jj];
      c0 += q1[(2*tp)*256 + k] * w;
      c1 += q1[(2*tp + 1)*256 + k] * w;
    }
    float bb = b2[jj];
    q2[(((size_t)t0 + 2*tp)*32 + b)*128 + jj]     = fmaxf(c0 + bb, 0.f);
    q2[(((size_t)t0 + 2*tp + 1)*32 + b)*128 + jj] = fmaxf(c1 + bb, 0.f);
  }
}

__global__ __launch_bounds__(128) void k_out(
    const float* __restrict__ r2, const float* __restrict__ wo,
    const float* __restrict__ bo, float* __restrict__ out)
{
  const int tb = blockIdx.x;
  const int t = tb >> 5, b = tb & 31, tid = threadIdx.x;
  __shared__ float row[256];
  for (int i = tid; i < 256; i += 128) row[i] = r2[(size_t)tb*256 + i];
  __syncthreads();
  if (tid < 80) {
    float acc = bo[tid];
    #pragma unroll 4
    for (int k = 0; k < 256; ++k) acc += row[k] * wo[(size_t)k*80 + tid];
    out[((size_t)b*TDEC + t)*80 + tid] = acc;
  }
}

// ---------------------------------------------------------------------------
extern "C" void kernel_launch(void* const* d_in, const int* in_sizes, int n_in,
                              void* d_out, int out_size, void* d_ws, size_t ws_size,
                              hipStream_t stream)
{
  const float* mem = (const float*)d_in[0];
  const float* dec = (const float*)d_in[1];
  const float* w1  = (const float*)d_in[2];
  const float* b1  = (const float*)d_in[3];
  const float* w2  = (const float*)d_in[4];
  const float* b2  = (const float*)d_in[5];
  const float* aK  = (const float*)d_in[6];
  const float* aRK = (const float*)d_in[7];
  const float* aB  = (const float*)d_in[8];
  const float* W   = (const float*)d_in[9];
  const float* U   = (const float*)d_in[10];
  const float* V   = (const float*)d_in[11];
  const float* Wp  = (const float*)d_in[12];
  const float* pb  = (const float*)d_in[13];
  const float* K1  = (const float*)d_in[14];
  const float* RK1 = (const float*)d_in[15];
  const float* B1v = (const float*)d_in[16];
  const float* K2  = (const float*)d_in[17];
  const float* RK2 = (const float*)d_in[18];
  const float* B2v = (const float*)d_in[19];
  const float* Wo  = (const float*)d_in[20];
  const float* bo  = (const float*)d_in[21];
  float* ws  = (float*)d_ws;
  float* out = (float*)d_out;

  hipMemsetAsync(ws, 0, (size_t)ZERO_FLOATS * sizeof(float), stream);
  k_prep<<<dim3(2592, 4), 256, 0, stream>>>(aK, aRK, Wp, K1, RK1, K2, RK2,
                                            (unsigned short*)(ws + O_IMG));
  k_wv<<<dim3(25, 32), 256, 0, stream>>>(mem, W, ws + O_WV);
  k_prenet<<<dim3(50, 32), 256, 0, stream>>>(dec, w1, b1, w2, b2, ws + O_Q2);
  k_scan6<<<224, 256, 0, stream>>>(mem, aB, U, V, pb, B1v, B2v, ws);
  k_out<<<6400, 128, 0, stream>>>(ws + O_R2S, Wo, bo, out);
}